// Round 2
// 2287.282 us; speedup vs baseline: 2.5817x; 2.5817x over previous
//
#include <hip/hip_runtime.h>

typedef _Float16 h16;
typedef _Float16 f16x8 __attribute__((ext_vector_type(8)));
typedef float f32x4 __attribute__((ext_vector_type(4)));

__device__ __forceinline__ float b2f(h16 v){ return (float)v; }
__device__ __forceinline__ h16 f2b(float v){ return (h16)v; }

#define CDIM 256
#define NHEADS 8
#define DH 32

// ---------------- weight transpose+convert: fp32 [K][N] -> f16 [N][K] ----------------
__global__ __launch_bounds__(256) void k_wt(const float* __restrict__ src, h16* __restrict__ dst,
                                            int K, int N)
{
    int n = blockIdx.x;
    for (int k = threadIdx.x; k < K; k += 256)
        dst[(long long)n * K + k] = f2b(src[(long long)k * N + n]);
}

// ---------------- NCHW (f32) -> NHWC (f16), LDS-tiled transpose ----------------
// grid: N * H * (W/64) * (C/64) blocks; 64c x 64w tile per block
__global__ __launch_bounds__(256) void k_nchw2nhwc(const float* __restrict__ x, h16* __restrict__ o,
                                                   int Hh, int Ww)
{
    __shared__ float T[64][65];
    int bid = blockIdx.x;
    int cb = bid & 3; bid >>= 2;            // C/64 == 4
    int nwb = Ww >> 6;
    int wb = bid % nwb; bid /= nwb;
    int h = bid % Hh;
    int n = bid / Hh;
    int lane = threadIdx.x & 63, grp = threadIdx.x >> 6;
    int w0 = wb << 6;
    long long HW = (long long)Hh * Ww;
    long long rbase = ((long long)(n * CDIM + cb * 64) * Hh + h) * Ww + w0;
    #pragma unroll
    for (int i = 0; i < 16; ++i) {
        int cl = grp * 16 + i;
        T[cl][lane] = x[rbase + (long long)cl * HW + lane];   // coalesced along w
    }
    __syncthreads();
    long long obase = (long long)(n * Hh + h) * Ww + w0;
    #pragma unroll
    for (int i = 0; i < 16; ++i) {
        int wl = grp * 16 + i;
        o[(obase + wl) * CDIM + cb * 64 + lane] = f2b(T[lane][wl]);  // coalesced along c
    }
}

// ---------------- MFMA GEMM: C[M,N] = A[M,K] @ B, with Bt[n][k] = B[k][n] (f16) ----------------
// 128x128 tile, BK=64, 4 waves (2x2), 16x16x32 f16 MFMA, global_load_lds staging.
__global__ __launch_bounds__(256) void k_gemm_mfma(const h16* __restrict__ A, const h16* __restrict__ Bt,
                                                   const float* __restrict__ bias, const h16* __restrict__ Cadd,
                                                   h16* __restrict__ C,
                                                   int M, int N, int K, int ldbt, int relu)
{
    __shared__ __align__(16) h16 As[128 * 64];
    __shared__ __align__(16) h16 Bs[128 * 64];
    const int tid = threadIdx.x;
    const int wave = tid >> 6, lane = tid & 63;
    const int row0 = blockIdx.y * 128, col0 = blockIdx.x * 128;
    const int wm = (wave >> 1) * 64, wn = (wave & 1) * 64;

    f32x4 acc[4][4] = {};

    // staging map: wave stages rows wave*32 + i*8 + (lane>>3), k = (lane&7)*8 .. +7
    const int srow = wave * 32 + (lane >> 3);
    const int skel = (lane & 7) * 8;
    const h16* ag = A  + (long long)(row0 + srow) * K    + skel;
    const h16* bg = Bt + (long long)(col0 + srow) * ldbt + skel;
    h16* as_base = As + (wave * 32) * 64;   // wave-uniform LDS base; HW adds lane*16B
    h16* bs_base = Bs + (wave * 32) * 64;

    for (int k0 = 0; k0 < K; k0 += 64) {
        #pragma unroll
        for (int i = 0; i < 4; ++i) {
            __builtin_amdgcn_global_load_lds(
                (const __attribute__((address_space(1))) void*)(ag + (long long)i * 8 * K),
                (__attribute__((address_space(3))) void*)(as_base + i * 8 * 64), 16, 0, 0);
            __builtin_amdgcn_global_load_lds(
                (const __attribute__((address_space(1))) void*)(bg + (long long)i * 8 * ldbt),
                (__attribute__((address_space(3))) void*)(bs_base + i * 8 * 64), 16, 0, 0);
        }
        ag += 64; bg += 64;
        __syncthreads();   // compiler drains vmcnt before barrier
        #pragma unroll
        for (int kk = 0; kk < 2; ++kk) {
            const int ko = kk * 32 + (lane >> 4) * 8;
            f16x8 af[4], bb[4];
            #pragma unroll
            for (int i = 0; i < 4; ++i) {
                af[i] = *(const f16x8*)(As + (wm + i * 16 + (lane & 15)) * 64 + ko);
                bb[i] = *(const f16x8*)(Bs + (wn + i * 16 + (lane & 15)) * 64 + ko);
            }
            #pragma unroll
            for (int i = 0; i < 4; ++i)
                #pragma unroll
                for (int j = 0; j < 4; ++j)
                    acc[i][j] = __builtin_amdgcn_mfma_f32_16x16x32_f16(af[i], bb[j], acc[i][j], 0, 0, 0);
        }
        __syncthreads();
    }

    // C/D layout: col = lane&15, row = (lane>>4)*4 + r
    const int cr = (lane >> 4) * 4;
    const int cc = lane & 15;
    #pragma unroll
    for (int j = 0; j < 4; ++j) {
        int col = col0 + wn + j * 16 + cc;
        float bv = bias ? bias[col] : 0.f;
        #pragma unroll
        for (int i = 0; i < 4; ++i) {
            #pragma unroll
            for (int r = 0; r < 4; ++r) {
                long long row = row0 + wm + i * 16 + cr + r;
                float v = acc[i][j][r] + bv;
                if (relu) v = fmaxf(v, 0.f);
                if (Cadd) v += b2f(Cadd[row * N + col]);
                C[row * N + col] = f2b(v);
            }
        }
    }
}

// ---------------- windowed self-attention (one block = one 8x8 window) ----------------
__global__ __launch_bounds__(256) void k_attn_self(const h16* __restrict__ Q, const h16* __restrict__ K,
                                                   const h16* __restrict__ V, h16* __restrict__ O,
                                                   int Hh, int Ww)
{
    __shared__ float sq[64][33], sk[64][33], sv[64][33];
    __shared__ float S[64][65];
    __shared__ int toki[64];
    int tid = threadIdx.x;
    int nw = Ww >> 3, nh = Hh >> 3;
    int win = blockIdx.x;
    int n = win / (nh * nw);
    int rem = win - n * (nh * nw);
    int wi = rem / nw, wj = rem - (rem / nw) * nw;
    if (tid < 64) {
        int r = tid >> 3, c2 = tid & 7;
        toki[tid] = (n * Hh + wi * 8 + r) * Ww + wj * 8 + c2;
    }
    __syncthreads();
    const float scale = 0.17677669529663687f; // 1/sqrt(32)
    for (int h = 0; h < NHEADS; ++h) {
        for (int l = tid; l < 64 * 32; l += 256) {
            int t = l >> 5, d = l & 31;
            long long base = (long long)toki[t] * CDIM + h * DH + d;
            sq[t][d] = b2f(Q[base]);
            sk[t][d] = b2f(K[base]);
            sv[t][d] = b2f(V[base]);
        }
        __syncthreads();
        for (int l = tid; l < 64 * 64; l += 256) {
            int qi = l >> 6, ki = l & 63;
            float s = 0.f;
            #pragma unroll
            for (int d = 0; d < 32; ++d) s += sq[qi][d] * sk[ki][d];
            S[qi][ki] = s * scale;
        }
        __syncthreads();
        {   // wave-parallel softmax: 4 lanes per row, 16 cols each
            int r = tid >> 2, qq = tid & 3;
            int i0 = qq * 16;
            float m = -1e30f;
            #pragma unroll
            for (int i = 0; i < 16; ++i) m = fmaxf(m, S[r][i0 + i]);
            m = fmaxf(m, __shfl_xor(m, 1));
            m = fmaxf(m, __shfl_xor(m, 2));
            float sum = 0.f;
            #pragma unroll
            for (int i = 0; i < 16; ++i) { float e = __expf(S[r][i0 + i] - m); S[r][i0 + i] = e; sum += e; }
            sum += __shfl_xor(sum, 1);
            sum += __shfl_xor(sum, 2);
            float inv = 1.f / sum;
            #pragma unroll
            for (int i = 0; i < 16; ++i) S[r][i0 + i] *= inv;
        }
        __syncthreads();
        for (int l = tid; l < 64 * 32; l += 256) {
            int t = l >> 5, d = l & 31;
            float o = 0.f;
            #pragma unroll
            for (int k2 = 0; k2 < 64; ++k2) o += S[t][k2] * sv[k2][d];
            O[(long long)toki[t] * CDIM + h * DH + d] = f2b(o);
        }
        __syncthreads();
    }
}

// ---------------- cross-attention: Q map (8,128,128,C), KV map (8,32,32,C) ----------------
__global__ __launch_bounds__(256) void k_attn_cross(const h16* __restrict__ Q, const h16* __restrict__ Kc,
                                                    const h16* __restrict__ Vc, h16* __restrict__ O)
{
    __shared__ float sq[64][33], sk[64][33], sv[64][33];
    __shared__ float S[64][65];
    __shared__ int qtok[64], ktok[64];
    int tid = threadIdx.x;
    int win = blockIdx.x;
    int n = win >> 8, wi = (win >> 4) & 15, wj = win & 15;
    if (tid < 64) {
        int r = tid >> 3, c2 = tid & 7;
        qtok[tid] = (n * 128 + wi * 8 + r) * 128 + wj * 8 + c2;
        ktok[tid] = (n * 32 + ((wi * 2 + r) & 31)) * 32 + ((wj * 2 + c2) & 31); // circular pad
    }
    __syncthreads();
    const float scale = 0.17677669529663687f;
    for (int h = 0; h < NHEADS; ++h) {
        for (int l = tid; l < 64 * 32; l += 256) {
            int t = l >> 5, d = l & 31;
            sq[t][d] = b2f(Q[(long long)qtok[t] * CDIM + h * DH + d]);
            long long kb = (long long)ktok[t] * CDIM + h * DH + d;
            sk[t][d] = b2f(Kc[kb]);
            sv[t][d] = b2f(Vc[kb]);
        }
        __syncthreads();
        for (int l = tid; l < 64 * 64; l += 256) {
            int qi = l >> 6, ki = l & 63;
            float s = 0.f;
            #pragma unroll
            for (int d = 0; d < 32; ++d) s += sq[qi][d] * sk[ki][d];
            S[qi][ki] = s * scale;
        }
        __syncthreads();
        {
            int r = tid >> 2, qq = tid & 3;
            int i0 = qq * 16;
            float m = -1e30f;
            #pragma unroll
            for (int i = 0; i < 16; ++i) m = fmaxf(m, S[r][i0 + i]);
            m = fmaxf(m, __shfl_xor(m, 1));
            m = fmaxf(m, __shfl_xor(m, 2));
            float sum = 0.f;
            #pragma unroll
            for (int i = 0; i < 16; ++i) { float e = __expf(S[r][i0 + i] - m); S[r][i0 + i] = e; sum += e; }
            sum += __shfl_xor(sum, 1);
            sum += __shfl_xor(sum, 2);
            float inv = 1.f / sum;
            #pragma unroll
            for (int i = 0; i < 16; ++i) S[r][i0 + i] *= inv;
        }
        __syncthreads();
        for (int l = tid; l < 64 * 32; l += 256) {
            int t = l >> 5, d = l & 31;
            float o = 0.f;
            #pragma unroll
            for (int k2 = 0; k2 < 64; ++k2) o += S[t][k2] * sv[k2][d];
            O[(long long)qtok[t] * CDIM + h * DH + d] = f2b(o);
        }
        __syncthreads();
    }
}

// ---------------- LayerNorm(A + B) * g + beta -> f16 NHWC ----------------
__global__ __launch_bounds__(256) void k_ln(const h16* __restrict__ A, const h16* __restrict__ Bb,
                                            const float* __restrict__ g, const float* __restrict__ be,
                                            h16* __restrict__ O)
{
    __shared__ float red[8];
    __shared__ float mv[2];
    int tok = blockIdx.x, c = threadIdx.x;
    float v = b2f(A[(long long)tok * CDIM + c]) + b2f(Bb[(long long)tok * CDIM + c]);
    float s = v, s2 = v * v;
    #pragma unroll
    for (int off = 32; off > 0; off >>= 1) { s += __shfl_down(s, off); s2 += __shfl_down(s2, off); }
    int lane = threadIdx.x & 63, wv = threadIdx.x >> 6;
    if (lane == 0) { red[wv] = s; red[4 + wv] = s2; }
    __syncthreads();
    if (threadIdx.x == 0) {
        float ts = red[0] + red[1] + red[2] + red[3];
        float ts2 = red[4] + red[5] + red[6] + red[7];
        float mu = ts * (1.f / 256.f);
        mv[0] = mu; mv[1] = ts2 * (1.f / 256.f) - mu * mu;
    }
    __syncthreads();
    float y = (v - mv[0]) * rsqrtf(mv[1] + 1e-5f) * g[c] + be[c];
    O[(long long)tok * CDIM + c] = f2b(y);
}

// ---------------- final LayerNorm(A + B) -> FLOAT32 output, NHWC->NCHW ----------------
__global__ __launch_bounds__(256) void k_ln_out(const h16* __restrict__ A, const h16* __restrict__ Bb,
                                                const float* __restrict__ g, const float* __restrict__ be,
                                                float* __restrict__ O, int HW)
{
    __shared__ float red[8];
    __shared__ float mv[2];
    int tok = blockIdx.x, c = threadIdx.x;
    float v = b2f(A[(long long)tok * CDIM + c]) + b2f(Bb[(long long)tok * CDIM + c]);
    float s = v, s2 = v * v;
    #pragma unroll
    for (int off = 32; off > 0; off >>= 1) { s += __shfl_down(s, off); s2 += __shfl_down(s2, off); }
    int lane = threadIdx.x & 63, wv = threadIdx.x >> 6;
    if (lane == 0) { red[wv] = s; red[4 + wv] = s2; }
    __syncthreads();
    if (threadIdx.x == 0) {
        float ts = red[0] + red[1] + red[2] + red[3];
        float ts2 = red[4] + red[5] + red[6] + red[7];
        float mu = ts * (1.f / 256.f);
        mv[0] = mu; mv[1] = ts2 * (1.f / 256.f) - mu * mu;
    }
    __syncthreads();
    float y = (v - mv[0]) * rsqrtf(mv[1] + 1e-5f) * g[c] + be[c];
    int n = tok / HW, hw = tok - n * HW;
    O[((long long)n * CDIM + c) * HW + hw] = y;   // fp32 NCHW output
}

// ---------------- 4x4 average pool ----------------
__global__ __launch_bounds__(256) void k_pool(const h16* __restrict__ A, h16* __restrict__ P,
                                              int Hin, int Win)
{
    int tok = blockIdx.x, c = threadIdx.x;
    int Wo = Win >> 2, Ho = Hin >> 2;
    int n = tok / (Ho * Wo);
    int rem = tok - n * (Ho * Wo);
    int i = rem / Wo, j = rem - (rem / Wo) * Wo;
    float s = 0.f;
    #pragma unroll
    for (int di = 0; di < 4; ++di)
        #pragma unroll
        for (int dj = 0; dj < 4; ++dj)
            s += b2f(A[(((long long)n * Hin + i * 4 + di) * Win + j * 4 + dj) * CDIM + c]);
    P[(long long)tok * CDIM + c] = f2b(s * 0.0625f);
}

extern "C" void kernel_launch(void* const* d_in, const int* in_sizes, int n_in,
                              void* d_out, int out_size, void* d_ws, size_t ws_size,
                              hipStream_t stream)
{
    const float* x     = (const float*)d_in[0];
    const float* sa_wq = (const float*)d_in[1];
    const float* sa_wk = (const float*)d_in[2];
    const float* sa_wv = (const float*)d_in[3];
    const float* sa_wf = (const float*)d_in[4];
    const float* sa_bf = (const float*)d_in[5];
    const float* ca_wq = (const float*)d_in[6];
    const float* ca_wk = (const float*)d_in[7];
    const float* ca_wv = (const float*)d_in[8];
    const float* ca_wf = (const float*)d_in[9];
    const float* ca_bf = (const float*)d_in[10];
    const float* lns_g = (const float*)d_in[11];
    const float* lns_b = (const float*)d_in[12];
    const float* lnc_g = (const float*)d_in[13];
    const float* lnc_b = (const float*)d_in[14];
    const float* w1    = (const float*)d_in[15];
    const float* b1    = (const float*)d_in[16];
    const float* w2    = (const float*)d_in[17];
    const float* b2    = (const float*)d_in[18];
    const float* lno_g = (const float*)d_in[19];
    const float* lno_b = (const float*)d_in[20];
    float* out = (float*)d_out;   // fp32 output, per reference dtype

    const int TOK0 = 8 * 128 * 128;   // 131072
    const int TOK1 = 8 * 32 * 32;     // 8192
    const size_t S0  = (size_t)TOK0 * CDIM * sizeof(h16); // 64 MiB
    const size_t SML = (size_t)TOK1 * CDIM * sizeof(h16); // 4 MiB
    char* ws = (char*)d_ws;
    // Peak workspace: 4 * 64 MiB = 256 MiB for activations.
    h16* W0 = (h16*)(ws);
    h16* W1 = (h16*)(ws + S0);
    h16* W2 = (h16*)(ws + 2 * S0);
    h16* W3 = (h16*)(ws + 3 * S0);
    // small (TOK1) buffers packed inside W0 once W0 is dead:
    h16* P1 = (h16*)(ws + 0 * SML);
    h16* Q1 = (h16*)(ws + 1 * SML);
    h16* K1 = (h16*)(ws + 2 * SML);
    h16* V1 = (h16*)(ws + 3 * SML);
    h16* J1 = (h16*)(ws + 4 * SML);
    h16* A1 = (h16*)(ws + 5 * SML);
    h16* Kc = (h16*)(ws + 6 * SML);
    h16* Vc = (h16*)(ws + 7 * SML);

    // Transposed f16 weights (2 MiB total): prefer workspace tail if there's slack,
    // else fall back to d_out (dead as an output until the final k_ln_out overwrites all of it).
    const size_t WSC_BYTES = (8 * 65536 + 262144 + 262144) * sizeof(h16); // 2 MiB
    h16* wsc;
    if (ws_size >= 4 * S0 + WSC_BYTES)
        wsc = (h16*)(ws + 4 * S0);
    else
        wsc = (h16*)d_out;
    h16* sa_wqT = wsc + 0 * 65536;
    h16* sa_wkT = wsc + 1 * 65536;
    h16* sa_wvT = wsc + 2 * 65536;
    h16* sa_wfT = wsc + 3 * 65536;
    h16* ca_wqT = wsc + 4 * 65536;
    h16* ca_wkT = wsc + 5 * 65536;
    h16* ca_wvT = wsc + 6 * 65536;
    h16* ca_wfT = wsc + 7 * 65536;
    h16* w1T    = wsc + 8 * 65536;            // [1024][256]
    h16* w2T    = wsc + 8 * 65536 + 262144;   // [256][1024]

    dim3 blk(256);
    dim3 g0(2, TOK0 / 128);   // N=256 tiles
    dim3 g1(2, TOK1 / 128);
    dim3 gH(4, TOK0 / 128);   // N=512 tiles

    // ---- weight prep ----
    k_wt<<<256,  blk, 0, stream>>>(sa_wq, sa_wqT, 256, 256);
    k_wt<<<256,  blk, 0, stream>>>(sa_wk, sa_wkT, 256, 256);
    k_wt<<<256,  blk, 0, stream>>>(sa_wv, sa_wvT, 256, 256);
    k_wt<<<256,  blk, 0, stream>>>(sa_wf, sa_wfT, 256, 256);
    k_wt<<<256,  blk, 0, stream>>>(ca_wq, ca_wqT, 256, 256);
    k_wt<<<256,  blk, 0, stream>>>(ca_wk, ca_wkT, 256, 256);
    k_wt<<<256,  blk, 0, stream>>>(ca_wv, ca_wvT, 256, 256);
    k_wt<<<256,  blk, 0, stream>>>(ca_wf, ca_wfT, 256, 256);
    k_wt<<<1024, blk, 0, stream>>>(w1, w1T, 256, 1024);
    k_wt<<<256,  blk, 0, stream>>>(w2, w2T, 1024, 256);

    // ---- level 0 self-attention ----
    k_nchw2nhwc<<<8 * 128 * 2 * 4, blk, 0, stream>>>(x, W0, 128, 128);
    k_gemm_mfma<<<g0, blk, 0, stream>>>(W0, sa_wqT, nullptr, nullptr, W1, TOK0, 256, 256, 256, 0);
    k_gemm_mfma<<<g0, blk, 0, stream>>>(W0, sa_wkT, nullptr, nullptr, W2, TOK0, 256, 256, 256, 0);
    k_gemm_mfma<<<g0, blk, 0, stream>>>(W0, sa_wvT, nullptr, nullptr, W3, TOK0, 256, 256, 256, 0);
    k_attn_self<<<TOK0 / 64, blk, 0, stream>>>(W1, W2, W3, W1, 128, 128);
    k_gemm_mfma<<<g0, blk, 0, stream>>>(W1, sa_wfT, sa_bf, nullptr, W2, TOK0, 256, 256, 256, 0);
    k_ln<<<TOK0, blk, 0, stream>>>(W0, W2, lns_g, lns_b, W3);                         // W3 = A0

    // ---- level 1 self-attention ----
    k_pool<<<TOK1, blk, 0, stream>>>(W3, P1, 128, 128);
    k_gemm_mfma<<<g1, blk, 0, stream>>>(P1, sa_wqT, nullptr, nullptr, Q1, TOK1, 256, 256, 256, 0);
    k_gemm_mfma<<<g1, blk, 0, stream>>>(P1, sa_wkT, nullptr, nullptr, K1, TOK1, 256, 256, 256, 0);
    k_gemm_mfma<<<g1, blk, 0, stream>>>(P1, sa_wvT, nullptr, nullptr, V1, TOK1, 256, 256, 256, 0);
    k_attn_self<<<TOK1 / 64, blk, 0, stream>>>(Q1, K1, V1, Q1, 32, 32);
    k_gemm_mfma<<<g1, blk, 0, stream>>>(Q1, sa_wfT, sa_bf, nullptr, J1, TOK1, 256, 256, 256, 0);
    k_ln<<<TOK1, blk, 0, stream>>>(P1, J1, lns_g, lns_b, A1);                         // A1

    // ---- cross-attention ----
    k_gemm_mfma<<<g0, blk, 0, stream>>>(W3, ca_wqT, nullptr, nullptr, W1, TOK0, 256, 256, 256, 0);
    k_gemm_mfma<<<g1, blk, 0, stream>>>(A1, ca_wkT, nullptr, nullptr, Kc, TOK1, 256, 256, 256, 0);
    k_gemm_mfma<<<g1, blk, 0, stream>>>(A1, ca_wvT, nullptr, nullptr, Vc, TOK1, 256, 256, 256, 0);
    k_attn_cross<<<TOK0 / 64, blk, 0, stream>>>(W1, Kc, Vc, W1);
    k_gemm_mfma<<<g0, blk, 0, stream>>>(W1, ca_wfT, ca_bf, nullptr, W2, TOK0, 256, 256, 256, 0);
    k_ln<<<TOK0, blk, 0, stream>>>(W3, W2, lnc_g, lnc_b, W1);                         // W1 = q

    // ---- FFN (hidden split 2x512, exact) + final LN -> fp32 NCHW ----
    k_gemm_mfma<<<gH, blk, 0, stream>>>(W1, w1T,             b1,       nullptr, W2, TOK0, 512, 256, 256, 1);
    k_gemm_mfma<<<g0, blk, 0, stream>>>(W2, w2T,             b2,       nullptr, W0, TOK0, 256, 512, 1024, 0);
    k_gemm_mfma<<<gH, blk, 0, stream>>>(W1, w1T + 512 * 256, b1 + 512, nullptr, W2, TOK0, 512, 256, 256, 1);
    k_gemm_mfma<<<g0, blk, 0, stream>>>(W2, w2T + 512,       nullptr,  W0,      W0, TOK0, 256, 512, 1024, 0);
    k_ln_out<<<TOK0, blk, 0, stream>>>(W1, W0, lno_g, lno_b, out, 128 * 128);
}

// Round 3
// 1516.314 us; speedup vs baseline: 3.8943x; 1.5084x over previous
//
#include <hip/hip_runtime.h>

typedef _Float16 h16;
typedef _Float16 f16x8 __attribute__((ext_vector_type(8)));
typedef _Float16 f16x4 __attribute__((ext_vector_type(4)));
typedef float f32x4 __attribute__((ext_vector_type(4)));

__device__ __forceinline__ float b2f(h16 v){ return (float)v; }
__device__ __forceinline__ h16 f2b(float v){ return (h16)v; }

#define CDIM 256
#define NHEADS 8
#define DH 32

// ---------------- weight transpose+convert: fp32 [K][N] -> f16 [N][K] ----------------
__global__ __launch_bounds__(256) void k_wt(const float* __restrict__ src, h16* __restrict__ dst,
                                            int K, int N)
{
    int n = blockIdx.x;
    for (int k = threadIdx.x; k < K; k += 256)
        dst[(long long)n * K + k] = f2b(src[(long long)k * N + n]);
}

// ---------------- NCHW (f32) -> NHWC (f16), LDS-tiled transpose ----------------
__global__ __launch_bounds__(256) void k_nchw2nhwc(const float* __restrict__ x, h16* __restrict__ o,
                                                   int Hh, int Ww)
{
    __shared__ float T[64][65];
    int bid = blockIdx.x;
    int cb = bid & 3; bid >>= 2;            // C/64 == 4
    int nwb = Ww >> 6;
    int wb = bid % nwb; bid /= nwb;
    int h = bid % Hh;
    int n = bid / Hh;
    int lane = threadIdx.x & 63, grp = threadIdx.x >> 6;
    int w0 = wb << 6;
    long long HW = (long long)Hh * Ww;
    long long rbase = ((long long)(n * CDIM + cb * 64) * Hh + h) * Ww + w0;
    #pragma unroll
    for (int i = 0; i < 16; ++i) {
        int cl = grp * 16 + i;
        T[cl][lane] = x[rbase + (long long)cl * HW + lane];
    }
    __syncthreads();
    long long obase = (long long)(n * Hh + h) * Ww + w0;
    #pragma unroll
    for (int i = 0; i < 16; ++i) {
        int wl = grp * 16 + i;
        o[(obase + wl) * CDIM + cb * 64 + lane] = f2b(T[lane][wl]);
    }
}

// ---------------- MFMA GEMM with output-group routing ----------------
// C addr = Cbase + (col>>8)*ostride + row*ldc + (col&255). Handles:
//   normal N<=256 (ostride ignored), fused QKV N=768 (3 buffers spaced ostride),
//   single wide buffer N=512/1024 (ostride=256, ldc=N).
__global__ __launch_bounds__(256) void k_gemm_mfma(const h16* __restrict__ A, const h16* __restrict__ Bt,
                                                   const float* __restrict__ bias, const h16* __restrict__ Cadd,
                                                   h16* __restrict__ C,
                                                   int M, int N, int K, int ldbt, int ldc,
                                                   long long ostride, int relu)
{
    __shared__ __align__(16) h16 As[128 * 64];
    __shared__ __align__(16) h16 Bs[128 * 64];
    const int tid = threadIdx.x;
    const int wave = tid >> 6, lane = tid & 63;
    const int row0 = blockIdx.y * 128, col0 = blockIdx.x * 128;
    const int wm = (wave >> 1) * 64, wn = (wave & 1) * 64;

    f32x4 acc[4][4] = {};

    const int srow = wave * 32 + (lane >> 3);
    const int skel = (lane & 7) * 8;
    const h16* ag = A  + (long long)(row0 + srow) * K    + skel;
    const h16* bg = Bt + (long long)(col0 + srow) * ldbt + skel;
    h16* as_base = As + (wave * 32) * 64;
    h16* bs_base = Bs + (wave * 32) * 64;

    for (int k0 = 0; k0 < K; k0 += 64) {
        #pragma unroll
        for (int i = 0; i < 4; ++i) {
            __builtin_amdgcn_global_load_lds(
                (const __attribute__((address_space(1))) void*)(ag + (long long)i * 8 * K),
                (__attribute__((address_space(3))) void*)(as_base + i * 8 * 64), 16, 0, 0);
            __builtin_amdgcn_global_load_lds(
                (const __attribute__((address_space(1))) void*)(bg + (long long)i * 8 * ldbt),
                (__attribute__((address_space(3))) void*)(bs_base + i * 8 * 64), 16, 0, 0);
        }
        ag += 64; bg += 64;
        __syncthreads();
        #pragma unroll
        for (int kk = 0; kk < 2; ++kk) {
            const int ko = kk * 32 + (lane >> 4) * 8;
            f16x8 af[4], bb[4];
            #pragma unroll
            for (int i = 0; i < 4; ++i) {
                af[i] = *(const f16x8*)(As + (wm + i * 16 + (lane & 15)) * 64 + ko);
                bb[i] = *(const f16x8*)(Bs + (wn + i * 16 + (lane & 15)) * 64 + ko);
            }
            #pragma unroll
            for (int i = 0; i < 4; ++i)
                #pragma unroll
                for (int j = 0; j < 4; ++j)
                    acc[i][j] = __builtin_amdgcn_mfma_f32_16x16x32_f16(af[i], bb[j], acc[i][j], 0, 0, 0);
        }
        __syncthreads();
    }

    const int cr = (lane >> 4) * 4;
    const int cc = lane & 15;
    #pragma unroll
    for (int j = 0; j < 4; ++j) {
        int col = col0 + wn + j * 16 + cc;
        int grp = col >> 8;
        long long cb = (long long)grp * ostride + (col & 255);
        float bv = bias ? bias[col] : 0.f;
        #pragma unroll
        for (int i = 0; i < 4; ++i) {
            #pragma unroll
            for (int r = 0; r < 4; ++r) {
                long long row = row0 + wm + i * 16 + cr + r;
                float v = acc[i][j][r] + bv;
                if (relu) v = fmaxf(v, 0.f);
                long long addr = cb + row * ldc;
                if (Cadd) v += b2f(Cadd[addr]);
                C[addr] = f2b(v);
            }
        }
    }
}

// ---------------- MFMA windowed attention (self + cross) ----------------
// One block = one 8x8 window (64 tokens); 4 waves, wave w handles heads 2w, 2w+1.
// S^T = mfma(K,Q) -> q is lane-local -> in-register softmax (2 shuffles).
// P re-fragmented through per-wave XOR-swizzled LDS; V^T staged per-wave.
// No __syncthreads: waves fully independent.
__global__ __launch_bounds__(256) void k_attn_mfma(const h16* __restrict__ Q, const h16* __restrict__ Kp,
                                                   const h16* __restrict__ Vp, h16* __restrict__ O,
                                                   int Hh, int Ww, int cross)
{
    __shared__ __align__(16) h16 SpA[4][64 * 64];   // P, per wave, 8 KiB
    __shared__ __align__(16) h16 VtA[4][32 * 64];   // V^T, per wave, 4 KiB
    const int tid = threadIdx.x;
    const int wave = tid >> 6, lane = tid & 63;
    const int l15 = lane & 15, g = lane >> 4;
    h16* Sp = SpA[wave];
    h16* Vt = VtA[wave];

    const int win = blockIdx.x;
    int n, wi, wj;
    if (cross) { n = win >> 8; wi = (win >> 4) & 15; wj = win & 15; }
    else {
        int nw = Ww >> 3, nh = Hh >> 3;
        n = win / (nh * nw);
        int rem = win - n * (nh * nw);
        wi = rem / nw; wj = rem - (rem / nw) * nw;
    }
    auto qtok = [&](int t) {
        return cross ? (n * 128 + wi * 8 + (t >> 3)) * 128 + wj * 8 + (t & 7)
                     : (n * Hh + wi * 8 + (t >> 3)) * Ww + wj * 8 + (t & 7);
    };
    auto ktok = [&](int t) {
        return cross ? (n * 32 + ((wi * 2 + (t >> 3)) & 31)) * 32 + ((wj * 2 + (t & 7)) & 31)
                     : qtok(t);
    };
    const float scale = 0.17677669529663687f;   // 1/sqrt(32)

    int qt_frag[4], kt_frag[4];
    #pragma unroll
    for (int i = 0; i < 4; ++i) { qt_frag[i] = qtok(i * 16 + l15); kt_frag[i] = ktok(i * 16 + l15); }
    const int vtok = ktok(lane);
    int otok[4][4];
    #pragma unroll
    for (int qt = 0; qt < 4; ++qt)
        #pragma unroll
        for (int rr = 0; rr < 4; ++rr)
            otok[qt][rr] = qtok(qt * 16 + g * 4 + rr);

    #pragma unroll 1
    for (int hh = 0; hh < 2; ++hh) {
        const int h = wave * 2 + hh;
        const int hoff = h * 32;

        // issue V loads early (hide HBM latency under QK^T)
        f16x8 vin[4];
        #pragma unroll
        for (int j = 0; j < 4; ++j)
            vin[j] = *(const f16x8*)(Vp + (long long)vtok * CDIM + hoff + j * 8);

        // K rows = A operand, Q rows = B operand
        f16x8 kf[4], qf[4];
        #pragma unroll
        for (int i = 0; i < 4; ++i) {
            kf[i] = *(const f16x8*)(Kp + (long long)kt_frag[i] * CDIM + hoff + g * 8);
            qf[i] = *(const f16x8*)(Q  + (long long)qt_frag[i] * CDIM + hoff + g * 8);
        }

        // stage V^T (transpose via LDS write): Vt[d][t], swizzled
        #pragma unroll
        for (int j = 0; j < 4; ++j)
            #pragma unroll
            for (int e = 0; e < 8; ++e) {
                int d = j * 8 + e;
                Vt[(d * 64 + lane) ^ ((d & 7) << 3)] = vin[j][e];
            }

        // S^T[k][q] = sum_d K[k][d] Q[q][d]
        f32x4 sT[4][4] = {};
        #pragma unroll
        for (int i = 0; i < 4; ++i)
            #pragma unroll
            for (int jq = 0; jq < 4; ++jq)
                sT[i][jq] = __builtin_amdgcn_mfma_f32_16x16x32_f16(kf[i], qf[jq], sT[i][jq], 0, 0, 0);

        // softmax per q (lane-local in k over i,rr; cross-group via shfl 16/32)
        #pragma unroll
        for (int jq = 0; jq < 4; ++jq) {
            float m = -1e30f;
            #pragma unroll
            for (int i = 0; i < 4; ++i)
                #pragma unroll
                for (int rr = 0; rr < 4; ++rr)
                    m = fmaxf(m, sT[i][jq][rr]);
            m = fmaxf(m, __shfl_xor(m, 16));
            m = fmaxf(m, __shfl_xor(m, 32));
            float p[16];
            float sum = 0.f;
            #pragma unroll
            for (int i = 0; i < 4; ++i)
                #pragma unroll
                for (int rr = 0; rr < 4; ++rr) {
                    float e = __expf((sT[i][jq][rr] - m) * scale);
                    p[i * 4 + rr] = e; sum += e;
                }
            sum += __shfl_xor(sum, 16);
            sum += __shfl_xor(sum, 32);
            float inv = 1.f / sum;
            int q = jq * 16 + l15;
            int rowbase = q * 64, swz = (q & 7) << 3;
            #pragma unroll
            for (int i = 0; i < 4; ++i) {
                f16x4 pk;
                pk[0] = (h16)(p[i * 4 + 0] * inv);
                pk[1] = (h16)(p[i * 4 + 1] * inv);
                pk[2] = (h16)(p[i * 4 + 2] * inv);
                pk[3] = (h16)(p[i * 4 + 3] * inv);
                *(f16x4*)(Sp + ((rowbase + i * 16 + g * 4) ^ swz)) = pk;   // P[q][k..k+3]
            }
        }
        // cross-lane LDS visibility (Vt + Sp) before PV reads
        asm volatile("s_waitcnt lgkmcnt(0)" ::: "memory");

        // O[q][d] = sum_k P[q][k] V[k][d]
        f32x4 o[4][2] = {};
        #pragma unroll
        for (int kb = 0; kb < 2; ++kb) {
            f16x8 vb[2];
            #pragma unroll
            for (int dt = 0; dt < 2; ++dt) {
                int d = dt * 16 + l15;
                vb[dt] = *(const f16x8*)(Vt + ((d * 64 + kb * 32 + g * 8) ^ ((d & 7) << 3)));
            }
            #pragma unroll
            for (int qt = 0; qt < 4; ++qt) {
                int q = qt * 16 + l15;
                f16x8 pa = *(const f16x8*)(Sp + ((q * 64 + kb * 32 + g * 8) ^ ((q & 7) << 3)));
                #pragma unroll
                for (int dt = 0; dt < 2; ++dt)
                    o[qt][dt] = __builtin_amdgcn_mfma_f32_16x16x32_f16(pa, vb[dt], o[qt][dt], 0, 0, 0);
            }
        }

        // store: col d = l15 -> 32B contiguous per token
        #pragma unroll
        for (int qt = 0; qt < 4; ++qt)
            #pragma unroll
            for (int rr = 0; rr < 4; ++rr) {
                long long tb = (long long)otok[qt][rr] * CDIM + hoff;
                #pragma unroll
                for (int dt = 0; dt < 2; ++dt)
                    O[tb + dt * 16 + l15] = f2b(o[qt][dt][rr]);
            }
        // WAR guard: next head reuses Sp/Vt
        asm volatile("s_waitcnt lgkmcnt(0)" ::: "memory");
    }
}

// ---------------- LayerNorm(A + B) * g + beta -> f16 NHWC ----------------
__global__ __launch_bounds__(256) void k_ln(const h16* __restrict__ A, const h16* __restrict__ Bb,
                                            const float* __restrict__ g, const float* __restrict__ be,
                                            h16* __restrict__ O)
{
    __shared__ float red[8];
    __shared__ float mv[2];
    int tok = blockIdx.x, c = threadIdx.x;
    float v = b2f(A[(long long)tok * CDIM + c]) + b2f(Bb[(long long)tok * CDIM + c]);
    float s = v, s2 = v * v;
    #pragma unroll
    for (int off = 32; off > 0; off >>= 1) { s += __shfl_down(s, off); s2 += __shfl_down(s2, off); }
    int lane = threadIdx.x & 63, wv = threadIdx.x >> 6;
    if (lane == 0) { red[wv] = s; red[4 + wv] = s2; }
    __syncthreads();
    if (threadIdx.x == 0) {
        float ts = red[0] + red[1] + red[2] + red[3];
        float ts2 = red[4] + red[5] + red[6] + red[7];
        float mu = ts * (1.f / 256.f);
        mv[0] = mu; mv[1] = ts2 * (1.f / 256.f) - mu * mu;
    }
    __syncthreads();
    float y = (v - mv[0]) * rsqrtf(mv[1] + 1e-5f) * g[c] + be[c];
    O[(long long)tok * CDIM + c] = f2b(y);
}

// ---------------- final LayerNorm(A + B) -> FLOAT32 output, NHWC->NCHW ----------------
__global__ __launch_bounds__(256) void k_ln_out(const h16* __restrict__ A, const h16* __restrict__ Bb,
                                                const float* __restrict__ g, const float* __restrict__ be,
                                                float* __restrict__ O, int HW)
{
    __shared__ float red[8];
    __shared__ float mv[2];
    int tok = blockIdx.x, c = threadIdx.x;
    float v = b2f(A[(long long)tok * CDIM + c]) + b2f(Bb[(long long)tok * CDIM + c]);
    float s = v, s2 = v * v;
    #pragma unroll
    for (int off = 32; off > 0; off >>= 1) { s += __shfl_down(s, off); s2 += __shfl_down(s2, off); }
    int lane = threadIdx.x & 63, wv = threadIdx.x >> 6;
    if (lane == 0) { red[wv] = s; red[4 + wv] = s2; }
    __syncthreads();
    if (threadIdx.x == 0) {
        float ts = red[0] + red[1] + red[2] + red[3];
        float ts2 = red[4] + red[5] + red[6] + red[7];
        float mu = ts * (1.f / 256.f);
        mv[0] = mu; mv[1] = ts2 * (1.f / 256.f) - mu * mu;
    }
    __syncthreads();
    float y = (v - mv[0]) * rsqrtf(mv[1] + 1e-5f) * g[c] + be[c];
    int n = tok / HW, hw = tok - n * HW;
    O[((long long)n * CDIM + c) * HW + hw] = y;
}

// ---------------- 4x4 average pool ----------------
__global__ __launch_bounds__(256) void k_pool(const h16* __restrict__ A, h16* __restrict__ P,
                                              int Hin, int Win)
{
    int tok = blockIdx.x, c = threadIdx.x;
    int Wo = Win >> 2, Ho = Hin >> 2;
    int n = tok / (Ho * Wo);
    int rem = tok - n * (Ho * Wo);
    int i = rem / Wo, j = rem - (rem / Wo) * Wo;
    float s = 0.f;
    #pragma unroll
    for (int di = 0; di < 4; ++di)
        #pragma unroll
        for (int dj = 0; dj < 4; ++dj)
            s += b2f(A[(((long long)n * Hin + i * 4 + di) * Win + j * 4 + dj) * CDIM + c]);
    P[(long long)tok * CDIM + c] = f2b(s * 0.0625f);
}

extern "C" void kernel_launch(void* const* d_in, const int* in_sizes, int n_in,
                              void* d_out, int out_size, void* d_ws, size_t ws_size,
                              hipStream_t stream)
{
    const float* x     = (const float*)d_in[0];
    const float* sa_wq = (const float*)d_in[1];
    const float* sa_wk = (const float*)d_in[2];
    const float* sa_wv = (const float*)d_in[3];
    const float* sa_wf = (const float*)d_in[4];
    const float* sa_bf = (const float*)d_in[5];
    const float* ca_wq = (const float*)d_in[6];
    const float* ca_wk = (const float*)d_in[7];
    const float* ca_wv = (const float*)d_in[8];
    const float* ca_wf = (const float*)d_in[9];
    const float* ca_bf = (const float*)d_in[10];
    const float* lns_g = (const float*)d_in[11];
    const float* lns_b = (const float*)d_in[12];
    const float* lnc_g = (const float*)d_in[13];
    const float* lnc_b = (const float*)d_in[14];
    const float* w1    = (const float*)d_in[15];
    const float* b1    = (const float*)d_in[16];
    const float* w2    = (const float*)d_in[17];
    const float* b2    = (const float*)d_in[18];
    const float* lno_g = (const float*)d_in[19];
    const float* lno_b = (const float*)d_in[20];
    float* out = (float*)d_out;

    const int TOK0 = 8 * 128 * 128;   // 131072
    const int TOK1 = 8 * 32 * 32;     // 8192
    const size_t S0  = (size_t)TOK0 * CDIM * sizeof(h16); // 64 MiB
    const size_t SML = (size_t)TOK1 * CDIM * sizeof(h16); // 4 MiB
    char* ws = (char*)d_ws;
    h16* W0 = (h16*)(ws);
    h16* W1 = (h16*)(ws + S0);
    h16* W2 = (h16*)(ws + 2 * S0);
    h16* W3 = (h16*)(ws + 3 * S0);
    h16* P1 = (h16*)(ws + 0 * SML);
    h16* Q1 = (h16*)(ws + 1 * SML);
    h16* K1 = (h16*)(ws + 2 * SML);
    h16* V1 = (h16*)(ws + 3 * SML);
    h16* J1 = (h16*)(ws + 4 * SML);
    h16* A1 = (h16*)(ws + 5 * SML);
    h16* Kc = (h16*)(ws + 6 * SML);
    h16* Vc = (h16*)(ws + 7 * SML);

    const size_t WSC_BYTES = (8 * 65536 + 262144 + 262144) * sizeof(h16); // 2 MiB
    h16* wsc;
    if (ws_size >= 4 * S0 + WSC_BYTES)
        wsc = (h16*)(ws + 4 * S0);
    else
        wsc = (h16*)d_out;
    h16* sa_wqT = wsc + 0 * 65536;   // [768][256] contiguous q,k,v
    h16* sa_wfT = wsc + 3 * 65536;
    h16* ca_wqT = wsc + 4 * 65536;
    h16* ca_wkT = wsc + 5 * 65536;   // [512][256] contiguous k,v
    h16* ca_wfT = wsc + 7 * 65536;
    h16* w1T    = wsc + 8 * 65536;            // [1024][256]
    h16* w2T    = wsc + 8 * 65536 + 262144;   // [256][1024]

    const long long OS0 = (long long)TOK0 * CDIM;   // spacing of W1/W2/W3 in elems
    const long long OS1 = (long long)TOK1 * CDIM;   // spacing of Q1/K1/V1, Kc/Vc

    dim3 blk(256);
    dim3 gQKV0(6, TOK0 / 128), gP0(2, TOK0 / 128);
    dim3 gQKV1(6, TOK1 / 128), gP1(2, TOK1 / 128);
    dim3 gKV(4, TOK1 / 128);
    dim3 gF1(4, TOK0 / 128), gF2(2, TOK0 / 128);

    // ---- weight prep ----
    k_wt<<<256,  blk, 0, stream>>>(sa_wq, wsc + 0 * 65536, 256, 256);
    k_wt<<<256,  blk, 0, stream>>>(sa_wk, wsc + 1 * 65536, 256, 256);
    k_wt<<<256,  blk, 0, stream>>>(sa_wv, wsc + 2 * 65536, 256, 256);
    k_wt<<<256,  blk, 0, stream>>>(sa_wf, sa_wfT, 256, 256);
    k_wt<<<256,  blk, 0, stream>>>(ca_wq, ca_wqT, 256, 256);
    k_wt<<<256,  blk, 0, stream>>>(ca_wk, ca_wkT, 256, 256);
    k_wt<<<256,  blk, 0, stream>>>(ca_wv, wsc + 6 * 65536, 256, 256);
    k_wt<<<256,  blk, 0, stream>>>(ca_wf, ca_wfT, 256, 256);
    k_wt<<<1024, blk, 0, stream>>>(w1, w1T, 256, 1024);
    k_wt<<<256,  blk, 0, stream>>>(w2, w2T, 1024, 256);

    // ---- level 0 self-attention ----
    k_nchw2nhwc<<<8 * 128 * 2 * 4, blk, 0, stream>>>(x, W0, 128, 128);
    k_gemm_mfma<<<gQKV0, blk, 0, stream>>>(W0, sa_wqT, nullptr, nullptr, W1, TOK0, 768, 256, 256, 256, OS0, 0);
    k_attn_mfma<<<TOK0 / 64, blk, 0, stream>>>(W1, W2, W3, W1, 128, 128, 0);
    k_gemm_mfma<<<gP0, blk, 0, stream>>>(W1, sa_wfT, sa_bf, nullptr, W2, TOK0, 256, 256, 256, 256, 0, 0);
    k_ln<<<TOK0, blk, 0, stream>>>(W0, W2, lns_g, lns_b, W3);                         // W3 = A0

    // ---- level 1 self-attention ----
    k_pool<<<TOK1, blk, 0, stream>>>(W3, P1, 128, 128);
    k_gemm_mfma<<<gQKV1, blk, 0, stream>>>(P1, sa_wqT, nullptr, nullptr, Q1, TOK1, 768, 256, 256, 256, OS1, 0);
    k_attn_mfma<<<TOK1 / 64, blk, 0, stream>>>(Q1, K1, V1, Q1, 32, 32, 0);
    k_gemm_mfma<<<gP1, blk, 0, stream>>>(Q1, sa_wfT, sa_bf, nullptr, J1, TOK1, 256, 256, 256, 256, 0, 0);
    k_ln<<<TOK1, blk, 0, stream>>>(P1, J1, lns_g, lns_b, A1);                         // A1

    // ---- cross-attention ----
    k_gemm_mfma<<<gP0, blk, 0, stream>>>(W3, ca_wqT, nullptr, nullptr, W1, TOK0, 256, 256, 256, 256, 0, 0);
    k_gemm_mfma<<<gKV, blk, 0, stream>>>(A1, ca_wkT, nullptr, nullptr, Kc, TOK1, 512, 256, 256, 256, OS1, 0);
    k_attn_mfma<<<TOK0 / 64, blk, 0, stream>>>(W1, Kc, Vc, W1, 0, 0, 1);
    k_gemm_mfma<<<gP0, blk, 0, stream>>>(W1, ca_wfT, ca_bf, nullptr, W2, TOK0, 256, 256, 256, 256, 0, 0);
    k_ln<<<TOK0, blk, 0, stream>>>(W3, W2, lnc_g, lnc_b, W1);                         // W1 = q

    // ---- FFN (hidden split 2x512) + final LN -> fp32 NCHW ----
    k_gemm_mfma<<<gF1, blk, 0, stream>>>(W1, w1T,             b1,       nullptr, W2, TOK0, 512, 256, 256, 512, 256, 1);
    k_gemm_mfma<<<gF2, blk, 0, stream>>>(W2, w2T,             b2,       nullptr, W0, TOK0, 256, 512, 1024, 256, 0, 0);
    k_gemm_mfma<<<gF1, blk, 0, stream>>>(W1, w1T + 512 * 256, b1 + 512, nullptr, W2, TOK0, 512, 256, 256, 512, 256, 1);
    k_gemm_mfma<<<gF2, blk, 0, stream>>>(W2, w2T + 512,       nullptr,  W0,      W0, TOK0, 256, 512, 1024, 256, 0, 0);
    k_ln_out<<<TOK0, blk, 0, stream>>>(W1, W0, lno_g, lno_b, out, 128 * 128);
}

// Round 4
// 1168.802 us; speedup vs baseline: 5.0522x; 1.2973x over previous
//
#include <hip/hip_runtime.h>

typedef _Float16 h16;
typedef _Float16 f16x8 __attribute__((ext_vector_type(8)));
typedef _Float16 f16x4 __attribute__((ext_vector_type(4)));
typedef float f32x4 __attribute__((ext_vector_type(4)));

__device__ __forceinline__ float b2f(h16 v){ return (float)v; }
__device__ __forceinline__ h16 f2b(float v){ return (h16)v; }

#define CDIM 256
#define NHEADS 8
#define DH 32

// ---------------- fused weight transpose+convert: all 10 weights, one launch ----------------
// fp32 [K][N] -> f16 [N][K], 32x32 LDS-tiled. 1024 blocks:
//   b in [0,512):  8 square 256x256 weights (64 tiles each)
//   b in [512,768): w1 256x1024 -> [1024][256]
//   b in [768,1024): w2 1024x256 -> [256][1024]
__global__ __launch_bounds__(256) void k_wt_all(const float* __restrict__ s0, const float* __restrict__ s1,
                                                const float* __restrict__ s2, const float* __restrict__ s3,
                                                const float* __restrict__ s4, const float* __restrict__ s5,
                                                const float* __restrict__ s6, const float* __restrict__ s7,
                                                const float* __restrict__ s8, const float* __restrict__ s9,
                                                h16* __restrict__ wsc)
{
    __shared__ float T[32][33];
    int b = blockIdx.x;
    const float* src; h16* dst; int K, N, ti, tj;
    if (b < 512) {
        int w = b >> 6, rem = b & 63;
        ti = rem >> 3; tj = rem & 7; K = 256; N = 256;
        switch (w) {
            case 0: src = s0; break; case 1: src = s1; break;
            case 2: src = s2; break; case 3: src = s3; break;
            case 4: src = s4; break; case 5: src = s5; break;
            case 6: src = s6; break; default: src = s7; break;
        }
        dst = wsc + w * 65536;
    } else if (b < 768) {
        int rem = b - 512; ti = rem >> 5; tj = rem & 31; K = 256; N = 1024;
        src = s8; dst = wsc + 8 * 65536;
    } else {
        int rem = b - 768; ti = rem >> 3; tj = rem & 7; K = 1024; N = 256;
        src = s9; dst = wsc + 8 * 65536 + 262144;
    }
    int rr = threadIdx.x >> 5, c = threadIdx.x & 31;
    #pragma unroll
    for (int i = 0; i < 4; ++i) {
        int r = i * 8 + rr;
        T[r][c] = src[(long long)(ti * 32 + r) * N + tj * 32 + c];   // coalesced along N
    }
    __syncthreads();
    #pragma unroll
    for (int i = 0; i < 4; ++i) {
        int r = i * 8 + rr;
        dst[(long long)(tj * 32 + r) * K + ti * 32 + c] = f2b(T[c][r]);  // coalesced along K
    }
}

// ---------------- NCHW (f32) -> NHWC (f16), LDS-tiled transpose ----------------
__global__ __launch_bounds__(256) void k_nchw2nhwc(const float* __restrict__ x, h16* __restrict__ o,
                                                   int Hh, int Ww)
{
    __shared__ float T[64][65];
    int bid = blockIdx.x;
    int cb = bid & 3; bid >>= 2;            // C/64 == 4
    int nwb = Ww >> 6;
    int wb = bid % nwb; bid /= nwb;
    int h = bid % Hh;
    int n = bid / Hh;
    int lane = threadIdx.x & 63, grp = threadIdx.x >> 6;
    int w0 = wb << 6;
    long long HW = (long long)Hh * Ww;
    long long rbase = ((long long)(n * CDIM + cb * 64) * Hh + h) * Ww + w0;
    #pragma unroll
    for (int i = 0; i < 16; ++i) {
        int cl = grp * 16 + i;
        T[cl][lane] = x[rbase + (long long)cl * HW + lane];
    }
    __syncthreads();
    long long obase = (long long)(n * Hh + h) * Ww + w0;
    #pragma unroll
    for (int i = 0; i < 16; ++i) {
        int wl = grp * 16 + i;
        o[(obase + wl) * CDIM + cb * 64 + lane] = f2b(T[lane][wl]);
    }
}

// ---------------- MFMA GEMM with output-group routing ----------------
// C addr = Cbase + (col>>8)*ostride + row*ldc + (col&255).
__global__ __launch_bounds__(256) void k_gemm_mfma(const h16* __restrict__ A, const h16* __restrict__ Bt,
                                                   const float* __restrict__ bias, const h16* __restrict__ Cadd,
                                                   h16* __restrict__ C,
                                                   int M, int N, int K, int ldbt, int ldc,
                                                   long long ostride, int relu)
{
    __shared__ __align__(16) h16 As[128 * 64];
    __shared__ __align__(16) h16 Bs[128 * 64];
    const int tid = threadIdx.x;
    const int wave = tid >> 6, lane = tid & 63;
    const int row0 = blockIdx.y * 128, col0 = blockIdx.x * 128;
    const int wm = (wave >> 1) * 64, wn = (wave & 1) * 64;

    f32x4 acc[4][4] = {};

    const int srow = wave * 32 + (lane >> 3);
    const int skel = (lane & 7) * 8;
    const h16* ag = A  + (long long)(row0 + srow) * K    + skel;
    const h16* bg = Bt + (long long)(col0 + srow) * ldbt + skel;
    h16* as_base = As + (wave * 32) * 64;
    h16* bs_base = Bs + (wave * 32) * 64;

    for (int k0 = 0; k0 < K; k0 += 64) {
        #pragma unroll
        for (int i = 0; i < 4; ++i) {
            __builtin_amdgcn_global_load_lds(
                (const __attribute__((address_space(1))) void*)(ag + (long long)i * 8 * K),
                (__attribute__((address_space(3))) void*)(as_base + i * 8 * 64), 16, 0, 0);
            __builtin_amdgcn_global_load_lds(
                (const __attribute__((address_space(1))) void*)(bg + (long long)i * 8 * ldbt),
                (__attribute__((address_space(3))) void*)(bs_base + i * 8 * 64), 16, 0, 0);
        }
        ag += 64; bg += 64;
        __syncthreads();
        #pragma unroll
        for (int kk = 0; kk < 2; ++kk) {
            const int ko = kk * 32 + (lane >> 4) * 8;
            f16x8 af[4], bb[4];
            #pragma unroll
            for (int i = 0; i < 4; ++i) {
                af[i] = *(const f16x8*)(As + (wm + i * 16 + (lane & 15)) * 64 + ko);
                bb[i] = *(const f16x8*)(Bs + (wn + i * 16 + (lane & 15)) * 64 + ko);
            }
            #pragma unroll
            for (int i = 0; i < 4; ++i)
                #pragma unroll
                for (int j = 0; j < 4; ++j)
                    acc[i][j] = __builtin_amdgcn_mfma_f32_16x16x32_f16(af[i], bb[j], acc[i][j], 0, 0, 0);
        }
        __syncthreads();
    }

    const int cr = (lane >> 4) * 4;
    const int cc = lane & 15;
    #pragma unroll
    for (int j = 0; j < 4; ++j) {
        int col = col0 + wn + j * 16 + cc;
        int grp = col >> 8;
        long long cb = (long long)grp * ostride + (col & 255);
        float bv = bias ? bias[col] : 0.f;
        #pragma unroll
        for (int i = 0; i < 4; ++i) {
            #pragma unroll
            for (int r = 0; r < 4; ++r) {
                long long row = row0 + wm + i * 16 + cr + r;
                float v = acc[i][j][r] + bv;
                if (relu) v = fmaxf(v, 0.f);
                long long addr = cb + row * ldc;
                if (Cadd) v += b2f(Cadd[addr]);
                C[addr] = f2b(v);
            }
        }
    }
}

// ---------------- MFMA windowed attention (self + cross) ----------------
__global__ __launch_bounds__(256) void k_attn_mfma(const h16* __restrict__ Q, const h16* __restrict__ Kp,
                                                   const h16* __restrict__ Vp, h16* __restrict__ O,
                                                   int Hh, int Ww, int cross)
{
    __shared__ __align__(16) h16 SpA[4][64 * 64];   // P, per wave, 8 KiB
    __shared__ __align__(16) h16 VtA[4][32 * 64];   // V^T, per wave, 4 KiB
    const int tid = threadIdx.x;
    const int wave = tid >> 6, lane = tid & 63;
    const int l15 = lane & 15, g = lane >> 4;
    h16* Sp = SpA[wave];
    h16* Vt = VtA[wave];

    const int win = blockIdx.x;
    int n, wi, wj;
    if (cross) { n = win >> 8; wi = (win >> 4) & 15; wj = win & 15; }
    else {
        int nw = Ww >> 3, nh = Hh >> 3;
        n = win / (nh * nw);
        int rem = win - n * (nh * nw);
        wi = rem / nw; wj = rem - (rem / nw) * nw;
    }
    auto qtok = [&](int t) {
        return cross ? (n * 128 + wi * 8 + (t >> 3)) * 128 + wj * 8 + (t & 7)
                     : (n * Hh + wi * 8 + (t >> 3)) * Ww + wj * 8 + (t & 7);
    };
    auto ktok = [&](int t) {
        return cross ? (n * 32 + ((wi * 2 + (t >> 3)) & 31)) * 32 + ((wj * 2 + (t & 7)) & 31)
                     : qtok(t);
    };
    const float scale = 0.17677669529663687f;   // 1/sqrt(32)

    int qt_frag[4], kt_frag[4];
    #pragma unroll
    for (int i = 0; i < 4; ++i) { qt_frag[i] = qtok(i * 16 + l15); kt_frag[i] = ktok(i * 16 + l15); }
    const int vtok = ktok(lane);
    int otok[4][4];
    #pragma unroll
    for (int qt = 0; qt < 4; ++qt)
        #pragma unroll
        for (int rr = 0; rr < 4; ++rr)
            otok[qt][rr] = qtok(qt * 16 + g * 4 + rr);

    #pragma unroll 1
    for (int hh = 0; hh < 2; ++hh) {
        const int h = wave * 2 + hh;
        const int hoff = h * 32;

        f16x8 vin[4];
        #pragma unroll
        for (int j = 0; j < 4; ++j)
            vin[j] = *(const f16x8*)(Vp + (long long)vtok * CDIM + hoff + j * 8);

        f16x8 kf[4], qf[4];
        #pragma unroll
        for (int i = 0; i < 4; ++i) {
            kf[i] = *(const f16x8*)(Kp + (long long)kt_frag[i] * CDIM + hoff + g * 8);
            qf[i] = *(const f16x8*)(Q  + (long long)qt_frag[i] * CDIM + hoff + g * 8);
        }

        #pragma unroll
        for (int j = 0; j < 4; ++j)
            #pragma unroll
            for (int e = 0; e < 8; ++e) {
                int d = j * 8 + e;
                Vt[(d * 64 + lane) ^ ((d & 7) << 3)] = vin[j][e];
            }

        f32x4 sT[4][4] = {};
        #pragma unroll
        for (int i = 0; i < 4; ++i)
            #pragma unroll
            for (int jq = 0; jq < 4; ++jq)
                sT[i][jq] = __builtin_amdgcn_mfma_f32_16x16x32_f16(kf[i], qf[jq], sT[i][jq], 0, 0, 0);

        #pragma unroll
        for (int jq = 0; jq < 4; ++jq) {
            float m = -1e30f;
            #pragma unroll
            for (int i = 0; i < 4; ++i)
                #pragma unroll
                for (int rr = 0; rr < 4; ++rr)
                    m = fmaxf(m, sT[i][jq][rr]);
            m = fmaxf(m, __shfl_xor(m, 16));
            m = fmaxf(m, __shfl_xor(m, 32));
            float p[16];
            float sum = 0.f;
            #pragma unroll
            for (int i = 0; i < 4; ++i)
                #pragma unroll
                for (int rr = 0; rr < 4; ++rr) {
                    float e = __expf((sT[i][jq][rr] - m) * scale);
                    p[i * 4 + rr] = e; sum += e;
                }
            sum += __shfl_xor(sum, 16);
            sum += __shfl_xor(sum, 32);
            float inv = 1.f / sum;
            int q = jq * 16 + l15;
            int rowbase = q * 64, swz = (q & 7) << 3;
            #pragma unroll
            for (int i = 0; i < 4; ++i) {
                f16x4 pk;
                pk[0] = (h16)(p[i * 4 + 0] * inv);
                pk[1] = (h16)(p[i * 4 + 1] * inv);
                pk[2] = (h16)(p[i * 4 + 2] * inv);
                pk[3] = (h16)(p[i * 4 + 3] * inv);
                *(f16x4*)(Sp + ((rowbase + i * 16 + g * 4) ^ swz)) = pk;
            }
        }
        asm volatile("s_waitcnt lgkmcnt(0)" ::: "memory");

        f32x4 o[4][2] = {};
        #pragma unroll
        for (int kb = 0; kb < 2; ++kb) {
            f16x8 vb[2];
            #pragma unroll
            for (int dt = 0; dt < 2; ++dt) {
                int d = dt * 16 + l15;
                vb[dt] = *(const f16x8*)(Vt + ((d * 64 + kb * 32 + g * 8) ^ ((d & 7) << 3)));
            }
            #pragma unroll
            for (int qt = 0; qt < 4; ++qt) {
                int q = qt * 16 + l15;
                f16x8 pa = *(const f16x8*)(Sp + ((q * 64 + kb * 32 + g * 8) ^ ((q & 7) << 3)));
                #pragma unroll
                for (int dt = 0; dt < 2; ++dt)
                    o[qt][dt] = __builtin_amdgcn_mfma_f32_16x16x32_f16(pa, vb[dt], o[qt][dt], 0, 0, 0);
            }
        }

        #pragma unroll
        for (int qt = 0; qt < 4; ++qt)
            #pragma unroll
            for (int rr = 0; rr < 4; ++rr) {
                long long tb = (long long)otok[qt][rr] * CDIM + hoff;
                #pragma unroll
                for (int dt = 0; dt < 2; ++dt)
                    O[tb + dt * 16 + l15] = f2b(o[qt][dt][rr]);
            }
        asm volatile("s_waitcnt lgkmcnt(0)" ::: "memory");
    }
}

// ---------------- LayerNorm(A + B) * g + beta -> f16 NHWC (vectorized, 8 tok/block) ----------------
__global__ __launch_bounds__(256) void k_ln(const h16* __restrict__ A, const h16* __restrict__ Bb,
                                            const float* __restrict__ g, const float* __restrict__ be,
                                            h16* __restrict__ O)
{
    int tid = threadIdx.x;
    int t = tid >> 5;      // token 0..7 within block
    int j = tid & 31;      // 8-channel chunk
    long long base = ((long long)blockIdx.x * 8 + t) * CDIM + j * 8;
    f16x8 a = *(const f16x8*)(A + base);
    f16x8 b = *(const f16x8*)(Bb + base);
    float v[8]; float s = 0.f, s2 = 0.f;
    #pragma unroll
    for (int e = 0; e < 8; ++e) { float vv = b2f(a[e]) + b2f(b[e]); v[e] = vv; s += vv; s2 += vv * vv; }
    #pragma unroll
    for (int off = 1; off < 32; off <<= 1) { s += __shfl_xor(s, off); s2 += __shfl_xor(s2, off); }
    float mu = s * (1.f / 256.f);
    float inv = rsqrtf(s2 * (1.f / 256.f) - mu * mu + 1e-5f);
    f32x4 g0 = *(const f32x4*)(g + j * 8),  g1 = *(const f32x4*)(g + j * 8 + 4);
    f32x4 e0 = *(const f32x4*)(be + j * 8), e1 = *(const f32x4*)(be + j * 8 + 4);
    f16x8 y;
    #pragma unroll
    for (int e = 0; e < 4; ++e) y[e] = f2b((v[e] - mu) * inv * g0[e] + e0[e]);
    #pragma unroll
    for (int e = 0; e < 4; ++e) y[e + 4] = f2b((v[e + 4] - mu) * inv * g1[e] + e1[e]);
    *(f16x8*)(O + base) = y;
}

// ---------------- final LayerNorm(A + B) -> fp32 NCHW via LDS-tiled transposed write ----------------
// 32 tokens per block; phase 1: vectorized loads + LN into LDS; phase 2: coalesced NCHW stores.
__global__ __launch_bounds__(256) void k_ln_out(const h16* __restrict__ A, const h16* __restrict__ Bb,
                                                const float* __restrict__ g, const float* __restrict__ be,
                                                float* __restrict__ O, int HW)
{
    __shared__ float Y[32][257];
    int tid = threadIdx.x;
    int t = tid >> 5;      // token 0..7 within pass
    int j = tid & 31;      // 8-channel chunk
    long long tok0 = (long long)blockIdx.x * 32;
    f32x4 g0 = *(const f32x4*)(g + j * 8),  g1 = *(const f32x4*)(g + j * 8 + 4);
    f32x4 e0 = *(const f32x4*)(be + j * 8), e1 = *(const f32x4*)(be + j * 8 + 4);
    #pragma unroll
    for (int pass = 0; pass < 4; ++pass) {
        int ta = pass * 8 + t;
        long long base = (tok0 + ta) * CDIM + j * 8;
        f16x8 a = *(const f16x8*)(A + base);
        f16x8 b = *(const f16x8*)(Bb + base);
        float v[8]; float s = 0.f, s2 = 0.f;
        #pragma unroll
        for (int e = 0; e < 8; ++e) { float vv = b2f(a[e]) + b2f(b[e]); v[e] = vv; s += vv; s2 += vv * vv; }
        #pragma unroll
        for (int off = 1; off < 32; off <<= 1) { s += __shfl_xor(s, off); s2 += __shfl_xor(s2, off); }
        float mu = s * (1.f / 256.f);
        float inv = rsqrtf(s2 * (1.f / 256.f) - mu * mu + 1e-5f);
        #pragma unroll
        for (int e = 0; e < 4; ++e) Y[ta][j * 8 + e]     = (v[e] - mu) * inv * g0[e] + e0[e];
        #pragma unroll
        for (int e = 0; e < 4; ++e) Y[ta][j * 8 + 4 + e] = (v[e + 4] - mu) * inv * g1[e] + e1[e];
    }
    __syncthreads();
    int n = (int)(tok0 / HW);
    int hw0 = (int)(tok0 - (long long)n * HW);
    int tt = tid & 31;          // token within block
    int cw = tid >> 5;          // channel subgroup 0..7
    #pragma unroll
    for (int k = 0; k < 32; ++k) {
        int c = k * 8 + cw;
        O[((long long)(n * CDIM + c)) * HW + hw0 + tt] = Y[tt][c];   // 128B-coalesced per channel
    }
}

// ---------------- 4x4 average pool ----------------
__global__ __launch_bounds__(256) void k_pool(const h16* __restrict__ A, h16* __restrict__ P,
                                              int Hin, int Win)
{
    int tok = blockIdx.x, c = threadIdx.x;
    int Wo = Win >> 2, Ho = Hin >> 2;
    int n = tok / (Ho * Wo);
    int rem = tok - n * (Ho * Wo);
    int i = rem / Wo, j = rem - (rem / Wo) * Wo;
    float s = 0.f;
    #pragma unroll
    for (int di = 0; di < 4; ++di)
        #pragma unroll
        for (int dj = 0; dj < 4; ++dj)
            s += b2f(A[(((long long)n * Hin + i * 4 + di) * Win + j * 4 + dj) * CDIM + c]);
    P[(long long)tok * CDIM + c] = f2b(s * 0.0625f);
}

extern "C" void kernel_launch(void* const* d_in, const int* in_sizes, int n_in,
                              void* d_out, int out_size, void* d_ws, size_t ws_size,
                              hipStream_t stream)
{
    const float* x     = (const float*)d_in[0];
    const float* sa_wq = (const float*)d_in[1];
    const float* sa_wk = (const float*)d_in[2];
    const float* sa_wv = (const float*)d_in[3];
    const float* sa_wf = (const float*)d_in[4];
    const float* sa_bf = (const float*)d_in[5];
    const float* ca_wq = (const float*)d_in[6];
    const float* ca_wk = (const float*)d_in[7];
    const float* ca_wv = (const float*)d_in[8];
    const float* ca_wf = (const float*)d_in[9];
    const float* ca_bf = (const float*)d_in[10];
    const float* lns_g = (const float*)d_in[11];
    const float* lns_b = (const float*)d_in[12];
    const float* lnc_g = (const float*)d_in[13];
    const float* lnc_b = (const float*)d_in[14];
    const float* w1    = (const float*)d_in[15];
    const float* b1    = (const float*)d_in[16];
    const float* w2    = (const float*)d_in[17];
    const float* b2    = (const float*)d_in[18];
    const float* lno_g = (const float*)d_in[19];
    const float* lno_b = (const float*)d_in[20];
    float* out = (float*)d_out;

    const int TOK0 = 8 * 128 * 128;   // 131072
    const int TOK1 = 8 * 32 * 32;     // 8192
    const size_t S0  = (size_t)TOK0 * CDIM * sizeof(h16); // 64 MiB
    const size_t SML = (size_t)TOK1 * CDIM * sizeof(h16); // 4 MiB
    char* ws = (char*)d_ws;
    h16* W0 = (h16*)(ws);
    h16* W1 = (h16*)(ws + S0);
    h16* W2 = (h16*)(ws + 2 * S0);
    h16* W3 = (h16*)(ws + 3 * S0);
    h16* P1 = (h16*)(ws + 0 * SML);
    h16* Q1 = (h16*)(ws + 1 * SML);
    h16* K1 = (h16*)(ws + 2 * SML);
    h16* V1 = (h16*)(ws + 3 * SML);
    h16* J1 = (h16*)(ws + 4 * SML);
    h16* A1 = (h16*)(ws + 5 * SML);
    h16* Kc = (h16*)(ws + 6 * SML);
    h16* Vc = (h16*)(ws + 7 * SML);

    const size_t WSC_BYTES = (8 * 65536 + 262144 + 262144) * sizeof(h16); // 2 MiB
    h16* wsc;
    if (ws_size >= 4 * S0 + WSC_BYTES)
        wsc = (h16*)(ws + 4 * S0);
    else
        wsc = (h16*)d_out;
    h16* sa_wqT = wsc + 0 * 65536;   // [768][256] contiguous q,k,v
    h16* sa_wfT = wsc + 3 * 65536;
    h16* ca_wqT = wsc + 4 * 65536;
    h16* ca_wkT = wsc + 5 * 65536;   // [512][256] contiguous k,v
    h16* ca_wfT = wsc + 7 * 65536;
    h16* w1T    = wsc + 8 * 65536;            // [1024][256]
    h16* w2T    = wsc + 8 * 65536 + 262144;   // [256][1024]

    const long long OS0 = (long long)TOK0 * CDIM;   // spacing of W1/W2/W3 in elems
    const long long OS1 = (long long)TOK1 * CDIM;   // spacing of Q1/K1/V1, Kc/Vc

    dim3 blk(256);
    dim3 gQKV0(6, TOK0 / 128), gP0(2, TOK0 / 128);
    dim3 gQKV1(6, TOK1 / 128), gP1(2, TOK1 / 128);
    dim3 gKV(4, TOK1 / 128);
    dim3 gF1(4, TOK0 / 128), gF2(2, TOK0 / 128);

    // ---- weight prep: one fused launch ----
    k_wt_all<<<1024, blk, 0, stream>>>(sa_wq, sa_wk, sa_wv, sa_wf, ca_wq, ca_wk, ca_wv, ca_wf,
                                       w1, w2, wsc);

    // ---- level 0 self-attention ----
    k_nchw2nhwc<<<8 * 128 * 2 * 4, blk, 0, stream>>>(x, W0, 128, 128);
    k_gemm_mfma<<<gQKV0, blk, 0, stream>>>(W0, sa_wqT, nullptr, nullptr, W1, TOK0, 768, 256, 256, 256, OS0, 0);
    k_attn_mfma<<<TOK0 / 64, blk, 0, stream>>>(W1, W2, W3, W1, 128, 128, 0);
    k_gemm_mfma<<<gP0, blk, 0, stream>>>(W1, sa_wfT, sa_bf, nullptr, W2, TOK0, 256, 256, 256, 256, 0, 0);
    k_ln<<<TOK0 / 8, blk, 0, stream>>>(W0, W2, lns_g, lns_b, W3);                     // W3 = A0

    // ---- level 1 self-attention ----
    k_pool<<<TOK1, blk, 0, stream>>>(W3, P1, 128, 128);
    k_gemm_mfma<<<gQKV1, blk, 0, stream>>>(P1, sa_wqT, nullptr, nullptr, Q1, TOK1, 768, 256, 256, 256, OS1, 0);
    k_attn_mfma<<<TOK1 / 64, blk, 0, stream>>>(Q1, K1, V1, Q1, 32, 32, 0);
    k_gemm_mfma<<<gP1, blk, 0, stream>>>(Q1, sa_wfT, sa_bf, nullptr, J1, TOK1, 256, 256, 256, 256, 0, 0);
    k_ln<<<TOK1 / 8, blk, 0, stream>>>(P1, J1, lns_g, lns_b, A1);                     // A1

    // ---- cross-attention ----
    k_gemm_mfma<<<gP0, blk, 0, stream>>>(W3, ca_wqT, nullptr, nullptr, W1, TOK0, 256, 256, 256, 256, 0, 0);
    k_gemm_mfma<<<gKV, blk, 0, stream>>>(A1, ca_wkT, nullptr, nullptr, Kc, TOK1, 512, 256, 256, 256, OS1, 0);
    k_attn_mfma<<<TOK0 / 64, blk, 0, stream>>>(W1, Kc, Vc, W1, 0, 0, 1);
    k_gemm_mfma<<<gP0, blk, 0, stream>>>(W1, ca_wfT, ca_bf, nullptr, W2, TOK0, 256, 256, 256, 256, 0, 0);
    k_ln<<<TOK0 / 8, blk, 0, stream>>>(W3, W2, lnc_g, lnc_b, W1);                     // W1 = q

    // ---- FFN (hidden split 2x512) + final LN -> fp32 NCHW ----
    k_gemm_mfma<<<gF1, blk, 0, stream>>>(W1, w1T,             b1,       nullptr, W2, TOK0, 512, 256, 256, 512, 256, 1);
    k_gemm_mfma<<<gF2, blk, 0, stream>>>(W2, w2T,             b2,       nullptr, W0, TOK0, 256, 512, 1024, 256, 0, 0);
    k_gemm_mfma<<<gF1, blk, 0, stream>>>(W1, w1T + 512 * 256, b1 + 512, nullptr, W2, TOK0, 512, 256, 256, 512, 256, 1);
    k_gemm_mfma<<<gF2, blk, 0, stream>>>(W2, w2T + 512,       nullptr,  W0,      W0, TOK0, 256, 512, 1024, 256, 0, 0);
    k_ln_out<<<TOK0 / 32, blk, 0, stream>>>(W1, W0, lno_g, lno_b, out, 128 * 128);
}

// Round 5
// 1156.026 us; speedup vs baseline: 5.1080x; 1.0111x over previous
//
#include <hip/hip_runtime.h>

typedef _Float16 h16;
typedef _Float16 f16x8 __attribute__((ext_vector_type(8)));
typedef _Float16 f16x4 __attribute__((ext_vector_type(4)));
typedef float f32x4 __attribute__((ext_vector_type(4)));

__device__ __forceinline__ float b2f(h16 v){ return (float)v; }
__device__ __forceinline__ h16 f2b(float v){ return (h16)v; }

#define CDIM 256
#define NHEADS 8
#define DH 32

// ---------------- fused weight transpose+convert: all 10 weights, one launch ----------------
__global__ __launch_bounds__(256) void k_wt_all(const float* __restrict__ s0, const float* __restrict__ s1,
                                                const float* __restrict__ s2, const float* __restrict__ s3,
                                                const float* __restrict__ s4, const float* __restrict__ s5,
                                                const float* __restrict__ s6, const float* __restrict__ s7,
                                                const float* __restrict__ s8, const float* __restrict__ s9,
                                                h16* __restrict__ wsc)
{
    __shared__ float T[32][33];
    int b = blockIdx.x;
    const float* src; h16* dst; int K, N, ti, tj;
    if (b < 512) {
        int w = b >> 6, rem = b & 63;
        ti = rem >> 3; tj = rem & 7; K = 256; N = 256;
        switch (w) {
            case 0: src = s0; break; case 1: src = s1; break;
            case 2: src = s2; break; case 3: src = s3; break;
            case 4: src = s4; break; case 5: src = s5; break;
            case 6: src = s6; break; default: src = s7; break;
        }
        dst = wsc + w * 65536;
    } else if (b < 768) {
        int rem = b - 512; ti = rem >> 5; tj = rem & 31; K = 256; N = 1024;
        src = s8; dst = wsc + 8 * 65536;
    } else {
        int rem = b - 768; ti = rem >> 3; tj = rem & 7; K = 1024; N = 256;
        src = s9; dst = wsc + 8 * 65536 + 262144;
    }
    int rr = threadIdx.x >> 5, c = threadIdx.x & 31;
    #pragma unroll
    for (int i = 0; i < 4; ++i) {
        int r = i * 8 + rr;
        T[r][c] = src[(long long)(ti * 32 + r) * N + tj * 32 + c];
    }
    __syncthreads();
    #pragma unroll
    for (int i = 0; i < 4; ++i) {
        int r = i * 8 + rr;
        dst[(long long)(tj * 32 + r) * K + ti * 32 + c] = f2b(T[c][r]);
    }
}

// ---------------- NCHW (f32) -> NHWC (f16), LDS-tiled transpose ----------------
__global__ __launch_bounds__(256) void k_nchw2nhwc(const float* __restrict__ x, h16* __restrict__ o,
                                                   int Hh, int Ww)
{
    __shared__ float T[64][65];
    int bid = blockIdx.x;
    int cb = bid & 3; bid >>= 2;
    int nwb = Ww >> 6;
    int wb = bid % nwb; bid /= nwb;
    int h = bid % Hh;
    int n = bid / Hh;
    int lane = threadIdx.x & 63, grp = threadIdx.x >> 6;
    int w0 = wb << 6;
    long long HW = (long long)Hh * Ww;
    long long rbase = ((long long)(n * CDIM + cb * 64) * Hh + h) * Ww + w0;
    #pragma unroll
    for (int i = 0; i < 16; ++i) {
        int cl = grp * 16 + i;
        T[cl][lane] = x[rbase + (long long)cl * HW + lane];
    }
    __syncthreads();
    long long obase = (long long)(n * Hh + h) * Ww + w0;
    #pragma unroll
    for (int i = 0; i < 16; ++i) {
        int wl = grp * 16 + i;
        o[(obase + wl) * CDIM + cb * 64 + lane] = f2b(T[lane][wl]);
    }
}

// ---------------- MFMA GEMM: T1 XCD-remap + T2 both-sides LDS swizzle ----------------
// C addr = Cbase + (col>>8)*ostride + row*ldc + (col&255).
__global__ __launch_bounds__(256) void k_gemm_mfma(const h16* __restrict__ A, const h16* __restrict__ Bt,
                                                   const float* __restrict__ bias, const h16* __restrict__ Cadd,
                                                   h16* __restrict__ C,
                                                   int N, int K, int ldA, int ldbt, int ldc,
                                                   long long ostride, int relu)
{
    __shared__ __align__(16) h16 As[128 * 64];
    __shared__ __align__(16) h16 Bs[128 * 64];
    const int tid = threadIdx.x;
    const int wave = tid >> 6, lane = tid & 63;
    const int l15 = lane & 15, g = lane >> 4;
    // T1: XCD-contiguous remap (all our grids have nwg % 8 == 0)
    const int gx = gridDim.x;
    int L = blockIdx.y * gx + blockIdx.x;
    const int nwg = gx * gridDim.y;
    if ((nwg & 7) == 0) {
        const int cpx = nwg >> 3;
        L = (L & 7) * cpx + (L >> 3);
    }
    const int row0 = (L / gx) * 128, col0 = (L % gx) * 128;
    const int wm = (wave >> 1) * 64, wn = (wave & 1) * 64;

    f32x4 acc[4][4] = {};

    // staging: wave stages rows wave*32 + i*8 + (lane>>3); source chunk pre-swizzled (T2 write side)
    const int srow = wave * 32 + (lane >> 3);
    const int sch  = ((lane & 7) ^ (srow & 7)) * 8;
    const h16* ag = A  + (long long)(row0 + srow) * ldA  + sch;
    const h16* bg = Bt + (long long)(col0 + srow) * ldbt + sch;
    h16* as_base = As + (wave * 32) * 64;
    h16* bs_base = Bs + (wave * 32) * 64;

    for (int k0 = 0; k0 < K; k0 += 64) {
        #pragma unroll
        for (int i = 0; i < 4; ++i) {
            __builtin_amdgcn_global_load_lds(
                (const __attribute__((address_space(1))) void*)(ag + (long long)i * 8 * ldA),
                (__attribute__((address_space(3))) void*)(as_base + i * 8 * 64), 16, 0, 0);
            __builtin_amdgcn_global_load_lds(
                (const __attribute__((address_space(1))) void*)(bg + (long long)i * 8 * ldbt),
                (__attribute__((address_space(3))) void*)(bs_base + i * 8 * 64), 16, 0, 0);
        }
        ag += 64; bg += 64;
        __syncthreads();
        #pragma unroll
        for (int kk = 0; kk < 2; ++kk) {
            const int c = kk * 4 + g;
            const int slot = (c ^ (l15 & 7)) << 3;   // T2 read side (same involution)
            f16x8 af[4], bb[4];
            #pragma unroll
            for (int i = 0; i < 4; ++i) {
                af[i] = *(const f16x8*)(As + (wm + i * 16 + l15) * 64 + slot);
                bb[i] = *(const f16x8*)(Bs + (wn + i * 16 + l15) * 64 + slot);
            }
            #pragma unroll
            for (int i = 0; i < 4; ++i)
                #pragma unroll
                for (int j = 0; j < 4; ++j)
                    acc[i][j] = __builtin_amdgcn_mfma_f32_16x16x32_f16(af[i], bb[j], acc[i][j], 0, 0, 0);
        }
        __syncthreads();
    }

    const int cr = g * 4;
    #pragma unroll
    for (int j = 0; j < 4; ++j) {
        int col = col0 + wn + j * 16 + l15;
        int grp = col >> 8;
        long long cb = (long long)grp * ostride + (col & 255);
        float bv = bias ? bias[col] : 0.f;
        #pragma unroll
        for (int i = 0; i < 4; ++i) {
            #pragma unroll
            for (int r = 0; r < 4; ++r) {
                long long row = row0 + wm + i * 16 + cr + r;
                float v = acc[i][j][r] + bv;
                if (relu) v = fmaxf(v, 0.f);
                long long addr = cb + row * ldc;
                if (Cadd) v += b2f(Cadd[addr]);
                C[addr] = f2b(v);
            }
        }
    }
}

// ---------------- MFMA GEMM (128 rows x 256 cols, 8 waves) + residual + LayerNorm epilogue ----------------
// u = acc + bias + Cadd + R;  y = LN(u)*g + b.
// mode 0: write f16 NHWC to O16. mode 1: write fp32 NCHW to O32 (f32x4 row-contiguous stores).
__global__ __launch_bounds__(512) void k_gemm_ln(const h16* __restrict__ A, const h16* __restrict__ Bt,
                                                 const float* __restrict__ bias, const h16* __restrict__ Cadd,
                                                 const h16* __restrict__ R,
                                                 const float* __restrict__ gw, const float* __restrict__ bw,
                                                 h16* __restrict__ O16, float* __restrict__ O32,
                                                 int K, int ldA, int ldbt, int HW, int mode)
{
    __shared__ __align__(16) h16 As[128 * 64];
    __shared__ __align__(16) h16 Bs[256 * 64];
    __shared__ float red[2][128][4];
    const int tid = threadIdx.x;
    const int wave = tid >> 6, lane = tid & 63;
    const int l15 = lane & 15, g = lane >> 4;
    const int row0 = blockIdx.x * 128;
    const int wm = (wave >> 2) * 64, wn = (wave & 3) * 64;

    f32x4 acc[4][4] = {};

    const int ar = wave * 16 + (lane >> 3);           // A rows: 2 stage iters
    const int br = wave * 32 + (lane >> 3);           // B rows: 4 stage iters
    const int ach = ((lane & 7) ^ (ar & 7)) * 8;
    const int bch = ((lane & 7) ^ (br & 7)) * 8;
    const h16* ag = A  + (long long)(row0 + ar) * ldA + ach;
    const h16* bg = Bt + (long long)br * ldbt + bch;
    h16* as_base = As + (wave * 16) * 64;
    h16* bs_base = Bs + (wave * 32) * 64;

    for (int k0 = 0; k0 < K; k0 += 64) {
        #pragma unroll
        for (int i = 0; i < 2; ++i)
            __builtin_amdgcn_global_load_lds(
                (const __attribute__((address_space(1))) void*)(ag + (long long)i * 8 * ldA),
                (__attribute__((address_space(3))) void*)(as_base + i * 8 * 64), 16, 0, 0);
        #pragma unroll
        for (int i = 0; i < 4; ++i)
            __builtin_amdgcn_global_load_lds(
                (const __attribute__((address_space(1))) void*)(bg + (long long)i * 8 * ldbt),
                (__attribute__((address_space(3))) void*)(bs_base + i * 8 * 64), 16, 0, 0);
        ag += 64; bg += 64;
        __syncthreads();
        #pragma unroll
        for (int kk = 0; kk < 2; ++kk) {
            const int c = kk * 4 + g;
            const int slot = (c ^ (l15 & 7)) << 3;
            f16x8 af[4], bb[4];
            #pragma unroll
            for (int i = 0; i < 4; ++i) {
                af[i] = *(const f16x8*)(As + (wm + i * 16 + l15) * 64 + slot);
                bb[i] = *(const f16x8*)(Bs + (wn + i * 16 + l15) * 64 + slot);
            }
            #pragma unroll
            for (int i = 0; i < 4; ++i)
                #pragma unroll
                for (int j = 0; j < 4; ++j)
                    acc[i][j] = __builtin_amdgcn_mfma_f32_16x16x32_f16(af[i], bb[j], acc[i][j], 0, 0, 0);
        }
        __syncthreads();
    }

    // epilogue: u = acc + bias + Cadd + R, per-token LN over 256 cols
    float sr[4][4] = {}, sr2[4][4] = {};
    #pragma unroll
    for (int j = 0; j < 4; ++j) {
        int col = wn + j * 16 + l15;
        float bv = bias ? bias[col] : 0.f;
        #pragma unroll
        for (int i = 0; i < 4; ++i) {
            #pragma unroll
            for (int r = 0; r < 4; ++r) {
                long long row = row0 + wm + i * 16 + g * 4 + r;
                float u = acc[i][j][r] + bv;
                if (Cadd) u += b2f(Cadd[row * CDIM + col]);
                u += b2f(R[row * CDIM + col]);
                acc[i][j][r] = u;
                sr[i][r] += u; sr2[i][r] += u * u;
            }
        }
    }
    #pragma unroll
    for (int i = 0; i < 4; ++i)
        #pragma unroll
        for (int r = 0; r < 4; ++r) {
            float s = sr[i][r], s2 = sr2[i][r];
            #pragma unroll
            for (int off = 1; off < 16; off <<= 1) { s += __shfl_xor(s, off); s2 += __shfl_xor(s2, off); }
            sr[i][r] = s; sr2[i][r] = s2;
        }
    if (l15 == 0) {
        #pragma unroll
        for (int i = 0; i < 4; ++i)
            #pragma unroll
            for (int r = 0; r < 4; ++r) {
                int lr = wm + i * 16 + g * 4 + r;
                red[0][lr][wave & 3] = sr[i][r];
                red[1][lr][wave & 3] = sr2[i][r];
            }
    }
    __syncthreads();
    float mu_[4][4], iv_[4][4];
    #pragma unroll
    for (int i = 0; i < 4; ++i)
        #pragma unroll
        for (int r = 0; r < 4; ++r) {
            int lr = wm + i * 16 + g * 4 + r;
            f32x4 p = *(const f32x4*)&red[0][lr][0];
            f32x4 q = *(const f32x4*)&red[1][lr][0];
            float ts  = p[0] + p[1] + p[2] + p[3];
            float ts2 = q[0] + q[1] + q[2] + q[3];
            float mu = ts * (1.f / 256.f);
            mu_[i][r] = mu;
            iv_[i][r] = rsqrtf(ts2 * (1.f / 256.f) - mu * mu + 1e-5f);
        }
    if (mode == 0) {
        #pragma unroll
        for (int j = 0; j < 4; ++j) {
            int col = wn + j * 16 + l15;
            float gc = gw[col], bc = bw[col];
            #pragma unroll
            for (int i = 0; i < 4; ++i)
                #pragma unroll
                for (int r = 0; r < 4; ++r) {
                    long long row = row0 + wm + i * 16 + g * 4 + r;
                    O16[row * CDIM + col] = f2b((acc[i][j][r] - mu_[i][r]) * iv_[i][r] * gc + bc);
                }
        }
    } else {
        #pragma unroll
        for (int j = 0; j < 4; ++j) {
            int col = wn + j * 16 + l15;
            float gc = gw[col], bc = bw[col];
            #pragma unroll
            for (int i = 0; i < 4; ++i) {
                int tok0 = row0 + wm + i * 16 + g * 4;
                int n = tok0 / HW, hw = tok0 - n * HW;
                f32x4 y;
                #pragma unroll
                for (int r = 0; r < 4; ++r)
                    y[r] = (acc[i][j][r] - mu_[i][r]) * iv_[i][r] * gc + bc;
                *(f32x4*)(O32 + (long long)(n * CDIM + col) * HW + hw) = y;
            }
        }
    }
}

// ---------------- MFMA windowed attention (self + cross) ----------------
__global__ __launch_bounds__(256) void k_attn_mfma(const h16* __restrict__ Q, const h16* __restrict__ Kp,
                                                   const h16* __restrict__ Vp, h16* __restrict__ O,
                                                   int Hh, int Ww, int cross)
{
    __shared__ __align__(16) h16 SpA[4][64 * 64];
    __shared__ __align__(16) h16 VtA[4][32 * 64];
    const int tid = threadIdx.x;
    const int wave = tid >> 6, lane = tid & 63;
    const int l15 = lane & 15, g = lane >> 4;
    h16* Sp = SpA[wave];
    h16* Vt = VtA[wave];

    const int win = blockIdx.x;
    int n, wi, wj;
    if (cross) { n = win >> 8; wi = (win >> 4) & 15; wj = win & 15; }
    else {
        int nw = Ww >> 3, nh = Hh >> 3;
        n = win / (nh * nw);
        int rem = win - n * (nh * nw);
        wi = rem / nw; wj = rem - (rem / nw) * nw;
    }
    auto qtok = [&](int t) {
        return cross ? (n * 128 + wi * 8 + (t >> 3)) * 128 + wj * 8 + (t & 7)
                     : (n * Hh + wi * 8 + (t >> 3)) * Ww + wj * 8 + (t & 7);
    };
    auto ktok = [&](int t) {
        return cross ? (n * 32 + ((wi * 2 + (t >> 3)) & 31)) * 32 + ((wj * 2 + (t & 7)) & 31)
                     : qtok(t);
    };
    const float scale = 0.17677669529663687f;

    int qt_frag[4], kt_frag[4];
    #pragma unroll
    for (int i = 0; i < 4; ++i) { qt_frag[i] = qtok(i * 16 + l15); kt_frag[i] = ktok(i * 16 + l15); }
    const int vtok = ktok(lane);
    int otok[4][4];
    #pragma unroll
    for (int qt = 0; qt < 4; ++qt)
        #pragma unroll
        for (int rr = 0; rr < 4; ++rr)
            otok[qt][rr] = qtok(qt * 16 + g * 4 + rr);

    #pragma unroll 1
    for (int hh = 0; hh < 2; ++hh) {
        const int h = wave * 2 + hh;
        const int hoff = h * 32;

        f16x8 vin[4];
        #pragma unroll
        for (int j = 0; j < 4; ++j)
            vin[j] = *(const f16x8*)(Vp + (long long)vtok * CDIM + hoff + j * 8);

        f16x8 kf[4], qf[4];
        #pragma unroll
        for (int i = 0; i < 4; ++i) {
            kf[i] = *(const f16x8*)(Kp + (long long)kt_frag[i] * CDIM + hoff + g * 8);
            qf[i] = *(const f16x8*)(Q  + (long long)qt_frag[i] * CDIM + hoff + g * 8);
        }

        #pragma unroll
        for (int j = 0; j < 4; ++j)
            #pragma unroll
            for (int e = 0; e < 8; ++e) {
                int d = j * 8 + e;
                Vt[(d * 64 + lane) ^ ((d & 7) << 3)] = vin[j][e];
            }

        f32x4 sT[4][4] = {};
        #pragma unroll
        for (int i = 0; i < 4; ++i)
            #pragma unroll
            for (int jq = 0; jq < 4; ++jq)
                sT[i][jq] = __builtin_amdgcn_mfma_f32_16x16x32_f16(kf[i], qf[jq], sT[i][jq], 0, 0, 0);

        #pragma unroll
        for (int jq = 0; jq < 4; ++jq) {
            float m = -1e30f;
            #pragma unroll
            for (int i = 0; i < 4; ++i)
                #pragma unroll
                for (int rr = 0; rr < 4; ++rr)
                    m = fmaxf(m, sT[i][jq][rr]);
            m = fmaxf(m, __shfl_xor(m, 16));
            m = fmaxf(m, __shfl_xor(m, 32));
            float p[16];
            float sum = 0.f;
            #pragma unroll
            for (int i = 0; i < 4; ++i)
                #pragma unroll
                for (int rr = 0; rr < 4; ++rr) {
                    float e = __expf((sT[i][jq][rr] - m) * scale);
                    p[i * 4 + rr] = e; sum += e;
                }
            sum += __shfl_xor(sum, 16);
            sum += __shfl_xor(sum, 32);
            float inv = 1.f / sum;
            int q = jq * 16 + l15;
            int rowbase = q * 64, swz = (q & 7) << 3;
            #pragma unroll
            for (int i = 0; i < 4; ++i) {
                f16x4 pk;
                pk[0] = (h16)(p[i * 4 + 0] * inv);
                pk[1] = (h16)(p[i * 4 + 1] * inv);
                pk[2] = (h16)(p[i * 4 + 2] * inv);
                pk[3] = (h16)(p[i * 4 + 3] * inv);
                *(f16x4*)(Sp + ((rowbase + i * 16 + g * 4) ^ swz)) = pk;
            }
        }
        asm volatile("s_waitcnt lgkmcnt(0)" ::: "memory");

        f32x4 o[4][2] = {};
        #pragma unroll
        for (int kb = 0; kb < 2; ++kb) {
            f16x8 vb[2];
            #pragma unroll
            for (int dt = 0; dt < 2; ++dt) {
                int d = dt * 16 + l15;
                vb[dt] = *(const f16x8*)(Vt + ((d * 64 + kb * 32 + g * 8) ^ ((d & 7) << 3)));
            }
            #pragma unroll
            for (int qt = 0; qt < 4; ++qt) {
                int q = qt * 16 + l15;
                f16x8 pa = *(const f16x8*)(Sp + ((q * 64 + kb * 32 + g * 8) ^ ((q & 7) << 3)));
                #pragma unroll
                for (int dt = 0; dt < 2; ++dt)
                    o[qt][dt] = __builtin_amdgcn_mfma_f32_16x16x32_f16(pa, vb[dt], o[qt][dt], 0, 0, 0);
            }
        }

        #pragma unroll
        for (int qt = 0; qt < 4; ++qt)
            #pragma unroll
            for (int rr = 0; rr < 4; ++rr) {
                long long tb = (long long)otok[qt][rr] * CDIM + hoff;
                #pragma unroll
                for (int dt = 0; dt < 2; ++dt)
                    O[tb + dt * 16 + l15] = f2b(o[qt][dt][rr]);
            }
        asm volatile("s_waitcnt lgkmcnt(0)" ::: "memory");
    }
}

// ---------------- final LayerNorm(A + B) -> fp32 NCHW (fallback path only) ----------------
__global__ __launch_bounds__(256) void k_ln_out(const h16* __restrict__ A, const h16* __restrict__ Bb,
                                                const float* __restrict__ g, const float* __restrict__ be,
                                                float* __restrict__ O, int HW)
{
    __shared__ float Y[32][257];
    int tid = threadIdx.x;
    int t = tid >> 5;
    int j = tid & 31;
    long long tok0 = (long long)blockIdx.x * 32;
    f32x4 g0 = *(const f32x4*)(g + j * 8),  g1 = *(const f32x4*)(g + j * 8 + 4);
    f32x4 e0 = *(const f32x4*)(be + j * 8), e1 = *(const f32x4*)(be + j * 8 + 4);
    #pragma unroll
    for (int pass = 0; pass < 4; ++pass) {
        int ta = pass * 8 + t;
        long long base = (tok0 + ta) * CDIM + j * 8;
        f16x8 a = *(const f16x8*)(A + base);
        f16x8 b = *(const f16x8*)(Bb + base);
        float v[8]; float s = 0.f, s2 = 0.f;
        #pragma unroll
        for (int e = 0; e < 8; ++e) { float vv = b2f(a[e]) + b2f(b[e]); v[e] = vv; s += vv; s2 += vv * vv; }
        #pragma unroll
        for (int off = 1; off < 32; off <<= 1) { s += __shfl_xor(s, off); s2 += __shfl_xor(s2, off); }
        float mu = s * (1.f / 256.f);
        float inv = rsqrtf(s2 * (1.f / 256.f) - mu * mu + 1e-5f);
        #pragma unroll
        for (int e = 0; e < 4; ++e) Y[ta][j * 8 + e]     = (v[e] - mu) * inv * g0[e] + e0[e];
        #pragma unroll
        for (int e = 0; e < 4; ++e) Y[ta][j * 8 + 4 + e] = (v[e + 4] - mu) * inv * g1[e] + e1[e];
    }
    __syncthreads();
    int n = (int)(tok0 / HW);
    int hw0 = (int)(tok0 - (long long)n * HW);
    int tt = tid & 31;
    int cw = tid >> 5;
    #pragma unroll
    for (int k = 0; k < 32; ++k) {
        int c = k * 8 + cw;
        O[((long long)(n * CDIM + c)) * HW + hw0 + tt] = Y[tt][c];
    }
}

// ---------------- 4x4 average pool ----------------
__global__ __launch_bounds__(256) void k_pool(const h16* __restrict__ A, h16* __restrict__ P,
                                              int Hin, int Win)
{
    int tok = blockIdx.x, c = threadIdx.x;
    int Wo = Win >> 2, Ho = Hin >> 2;
    int n = tok / (Ho * Wo);
    int rem = tok - n * (Ho * Wo);
    int i = rem / Wo, j = rem - (rem / Wo) * Wo;
    float s = 0.f;
    #pragma unroll
    for (int di = 0; di < 4; ++di)
        #pragma unroll
        for (int dj = 0; dj < 4; ++dj)
            s += b2f(A[(((long long)n * Hin + i * 4 + di) * Win + j * 4 + dj) * CDIM + c]);
    P[(long long)tok * CDIM + c] = f2b(s * 0.0625f);
}

extern "C" void kernel_launch(void* const* d_in, const int* in_sizes, int n_in,
                              void* d_out, int out_size, void* d_ws, size_t ws_size,
                              hipStream_t stream)
{
    const float* x     = (const float*)d_in[0];
    const float* sa_wq = (const float*)d_in[1];
    const float* sa_wk = (const float*)d_in[2];
    const float* sa_wv = (const float*)d_in[3];
    const float* sa_wf = (const float*)d_in[4];
    const float* sa_bf = (const float*)d_in[5];
    const float* ca_wq = (const float*)d_in[6];
    const float* ca_wk = (const float*)d_in[7];
    const float* ca_wv = (const float*)d_in[8];
    const float* ca_wf = (const float*)d_in[9];
    const float* ca_bf = (const float*)d_in[10];
    const float* lns_g = (const float*)d_in[11];
    const float* lns_b = (const float*)d_in[12];
    const float* lnc_g = (const float*)d_in[13];
    const float* lnc_b = (const float*)d_in[14];
    const float* w1    = (const float*)d_in[15];
    const float* b1    = (const float*)d_in[16];
    const float* w2    = (const float*)d_in[17];
    const float* b2    = (const float*)d_in[18];
    const float* lno_g = (const float*)d_in[19];
    const float* lno_b = (const float*)d_in[20];
    float* out = (float*)d_out;

    const int TOK0 = 8 * 128 * 128;   // 131072
    const int TOK1 = 8 * 32 * 32;     // 8192
    const size_t S0  = (size_t)TOK0 * CDIM * sizeof(h16); // 64 MiB
    const size_t SML = (size_t)TOK1 * CDIM * sizeof(h16); // 4 MiB
    char* ws = (char*)d_ws;
    h16* W0 = (h16*)(ws);
    h16* W1 = (h16*)(ws + S0);
    h16* W2 = (h16*)(ws + 2 * S0);
    h16* W3 = (h16*)(ws + 3 * S0);
    h16* H  = W2;                      // FFN hidden [TOK0][512], spans W2..W3
    h16* P1 = (h16*)(ws + 0 * SML);
    h16* Q1 = (h16*)(ws + 1 * SML);
    h16* K1 = (h16*)(ws + 2 * SML);
    h16* V1 = (h16*)(ws + 3 * SML);
    h16* A1 = (h16*)(ws + 5 * SML);
    h16* Kc = (h16*)(ws + 6 * SML);
    h16* Vc = (h16*)(ws + 7 * SML);

    const size_t WSC_BYTES = (8 * 65536 + 262144 + 262144) * sizeof(h16); // 2 MiB
    bool tailws = ws_size >= 4 * S0 + WSC_BYTES;
    h16* wsc = tailws ? (h16*)(ws + 4 * S0) : (h16*)d_out;
    h16* sa_wqT = wsc + 0 * 65536;   // [768][256] contiguous q,k,v
    h16* sa_wfT = wsc + 3 * 65536;
    h16* ca_wqT = wsc + 4 * 65536;
    h16* ca_wkT = wsc + 5 * 65536;   // [512][256] contiguous k,v
    h16* ca_wfT = wsc + 7 * 65536;
    h16* w1T    = wsc + 8 * 65536;            // [1024][256]
    h16* w2T    = wsc + 8 * 65536 + 262144;   // [256][1024]

    const long long OS0 = (long long)TOK0 * CDIM;
    const long long OS1 = (long long)TOK1 * CDIM;

    dim3 blk(256), blk2(512);

    // ---- weight prep ----
    k_wt_all<<<1024, blk, 0, stream>>>(sa_wq, sa_wk, sa_wv, sa_wf, ca_wq, ca_wk, ca_wv, ca_wf,
                                       w1, w2, wsc);

    // ---- level 0 self-attention ----
    k_nchw2nhwc<<<8 * 128 * 2 * 4, blk, 0, stream>>>(x, W0, 128, 128);
    k_gemm_mfma<<<dim3(6, TOK0 / 128), blk, 0, stream>>>(W0, sa_wqT, nullptr, nullptr, W1, 768, 256, 256, 256, 256, OS0, 0);
    k_attn_mfma<<<TOK0 / 64, blk, 0, stream>>>(W1, W2, W3, W1, 128, 128, 0);
    k_gemm_ln<<<TOK0 / 128, blk2, 0, stream>>>(W1, sa_wfT, sa_bf, nullptr, W0, lns_g, lns_b,
                                               W3, nullptr, 256, 256, 256, 16384, 0);      // W3 = A0

    // ---- level 1 self-attention ----
    k_pool<<<TOK1, blk, 0, stream>>>(W3, P1, 128, 128);
    k_gemm_mfma<<<dim3(6, TOK1 / 128), blk, 0, stream>>>(P1, sa_wqT, nullptr, nullptr, Q1, 768, 256, 256, 256, 256, OS1, 0);
    k_attn_mfma<<<TOK1 / 64, blk, 0, stream>>>(Q1, K1, V1, Q1, 32, 32, 0);
    k_gemm_ln<<<TOK1 / 128, blk2, 0, stream>>>(Q1, sa_wfT, sa_bf, nullptr, P1, lns_g, lns_b,
                                               A1, nullptr, 256, 256, 256, 1024, 0);       // A1

    // ---- cross-attention ----
    k_gemm_mfma<<<dim3(2, TOK0 / 128), blk, 0, stream>>>(W3, ca_wqT, nullptr, nullptr, W1, 256, 256, 256, 256, 256, 0, 0);
    k_gemm_mfma<<<dim3(4, TOK1 / 128), blk, 0, stream>>>(A1, ca_wkT, nullptr, nullptr, Kc, 512, 256, 256, 256, 256, OS1, 0);
    k_attn_mfma<<<TOK0 / 64, blk, 0, stream>>>(W1, Kc, Vc, W1, 0, 0, 1);
    k_gemm_ln<<<TOK0 / 128, blk2, 0, stream>>>(W1, ca_wfT, ca_bf, nullptr, W3, lnc_g, lnc_b,
                                               W1, nullptr, 256, 256, 256, 16384, 0);      // W1 = q

    // ---- FFN (hidden split 2x512 into H = W2..W3 span) + fused final LN -> fp32 NCHW ----
    k_gemm_mfma<<<dim3(4, TOK0 / 128), blk, 0, stream>>>(W1, w1T,             b1,       nullptr, H,  512, 256, 256, 256, 512, 256, 1);
    k_gemm_mfma<<<dim3(2, TOK0 / 128), blk, 0, stream>>>(H,  w2T,             b2,       nullptr, W0, 256, 512, 512, 1024, 256, 0, 0);
    k_gemm_mfma<<<dim3(4, TOK0 / 128), blk, 0, stream>>>(W1, w1T + 512 * 256, b1 + 512, nullptr, H,  512, 256, 256, 256, 512, 256, 1);
    if (tailws) {
        // fused: u = H@w2T(2nd half) + W0 + W1(residual); LN -> fp32 NCHW
        k_gemm_ln<<<TOK0 / 128, blk2, 0, stream>>>(H, w2T + 512, nullptr, W0, W1, lno_g, lno_b,
                                                   nullptr, out, 512, 512, 1024, 16384, 1);
    } else {
        // weights live in d_out -> cannot write out concurrently; two-step fallback
        k_gemm_mfma<<<dim3(2, TOK0 / 128), blk, 0, stream>>>(H, w2T + 512, nullptr, W0, W0, 256, 512, 512, 1024, 256, 0, 0);
        k_ln_out<<<TOK0 / 32, blk, 0, stream>>>(W1, W0, lno_g, lno_b, out, 16384);
    }
}

// Round 6
// 1128.498 us; speedup vs baseline: 5.2326x; 1.0244x over previous
//
#include <hip/hip_runtime.h>

typedef _Float16 h16;
typedef _Float16 f16x8 __attribute__((ext_vector_type(8)));
typedef _Float16 f16x4 __attribute__((ext_vector_type(4)));
typedef float f32x4 __attribute__((ext_vector_type(4)));

__device__ __forceinline__ float b2f(h16 v){ return (float)v; }
__device__ __forceinline__ h16 f2b(float v){ return (h16)v; }

#define CDIM 256
#define NHEADS 8
#define DH 32

// ---------------- fused weight transpose+convert: all 10 weights, one launch ----------------
__global__ __launch_bounds__(256) void k_wt_all(const float* __restrict__ s0, const float* __restrict__ s1,
                                                const float* __restrict__ s2, const float* __restrict__ s3,
                                                const float* __restrict__ s4, const float* __restrict__ s5,
                                                const float* __restrict__ s6, const float* __restrict__ s7,
                                                const float* __restrict__ s8, const float* __restrict__ s9,
                                                h16* __restrict__ wsc)
{
    __shared__ float T[32][33];
    int b = blockIdx.x;
    const float* src; h16* dst; int K, N, ti, tj;
    if (b < 512) {
        int w = b >> 6, rem = b & 63;
        ti = rem >> 3; tj = rem & 7; K = 256; N = 256;
        switch (w) {
            case 0: src = s0; break; case 1: src = s1; break;
            case 2: src = s2; break; case 3: src = s3; break;
            case 4: src = s4; break; case 5: src = s5; break;
            case 6: src = s6; break; default: src = s7; break;
        }
        dst = wsc + w * 65536;
    } else if (b < 768) {
        int rem = b - 512; ti = rem >> 5; tj = rem & 31; K = 256; N = 1024;
        src = s8; dst = wsc + 8 * 65536;
    } else {
        int rem = b - 768; ti = rem >> 3; tj = rem & 7; K = 1024; N = 256;
        src = s9; dst = wsc + 8 * 65536 + 262144;
    }
    int rr = threadIdx.x >> 5, c = threadIdx.x & 31;
    #pragma unroll
    for (int i = 0; i < 4; ++i) {
        int r = i * 8 + rr;
        T[r][c] = src[(long long)(ti * 32 + r) * N + tj * 32 + c];
    }
    __syncthreads();
    #pragma unroll
    for (int i = 0; i < 4; ++i) {
        int r = i * 8 + rr;
        dst[(long long)(tj * 32 + r) * K + ti * 32 + c] = f2b(T[c][r]);
    }
}

// ---------------- NCHW (f32) -> NHWC (f16), LDS-tiled transpose ----------------
__global__ __launch_bounds__(256) void k_nchw2nhwc(const float* __restrict__ x, h16* __restrict__ o,
                                                   int Hh, int Ww)
{
    __shared__ float T[64][65];
    int bid = blockIdx.x;
    int cb = bid & 3; bid >>= 2;
    int nwb = Ww >> 6;
    int wb = bid % nwb; bid /= nwb;
    int h = bid % Hh;
    int n = bid / Hh;
    int lane = threadIdx.x & 63, grp = threadIdx.x >> 6;
    int w0 = wb << 6;
    long long HW = (long long)Hh * Ww;
    long long rbase = ((long long)(n * CDIM + cb * 64) * Hh + h) * Ww + w0;
    #pragma unroll
    for (int i = 0; i < 16; ++i) {
        int cl = grp * 16 + i;
        T[cl][lane] = x[rbase + (long long)cl * HW + lane];
    }
    __syncthreads();
    long long obase = (long long)(n * Hh + h) * Ww + w0;
    #pragma unroll
    for (int i = 0; i < 16; ++i) {
        int wl = grp * 16 + i;
        o[(obase + wl) * CDIM + cb * 64 + lane] = f2b(T[lane][wl]);
    }
}

// ---------------- MFMA GEMM: T1 XCD-remap + T2 swizzle + T3 2-phase dbuf pipeline ----------------
// C addr = Cbase + (col>>8)*ostride + row*ldc + (col&255).
__global__ __launch_bounds__(256) void k_gemm_mfma(const h16* __restrict__ A, const h16* __restrict__ Bt,
                                                   const float* __restrict__ bias, const h16* __restrict__ Cadd,
                                                   h16* __restrict__ C,
                                                   int N, int K, int ldA, int ldbt, int ldc,
                                                   long long ostride, int relu)
{
    __shared__ __align__(16) h16 As[2 * 128 * 64];
    __shared__ __align__(16) h16 Bs[2 * 128 * 64];
    const int tid = threadIdx.x;
    const int wave = tid >> 6, lane = tid & 63;
    const int l15 = lane & 15, g = lane >> 4;
    // T1: XCD-contiguous remap (all our grids have nwg % 8 == 0)
    const int gx = gridDim.x;
    int L = blockIdx.y * gx + blockIdx.x;
    const int nwg = gx * gridDim.y;
    if ((nwg & 7) == 0) {
        const int cpx = nwg >> 3;
        L = (L & 7) * cpx + (L >> 3);
    }
    const int row0 = (L / gx) * 128, col0 = (L % gx) * 128;
    const int wm = (wave >> 1) * 64, wn = (wave & 1) * 64;

    f32x4 acc[4][4] = {};

    const int srow = wave * 32 + (lane >> 3);
    const int sch  = ((lane & 7) ^ (srow & 7)) * 8;
    const h16* ag = A  + (long long)(row0 + srow) * ldA  + sch;
    const h16* bg = Bt + (long long)(col0 + srow) * ldbt + sch;
    h16* as_base = As + (wave * 32) * 64;
    h16* bs_base = Bs + (wave * 32) * 64;

    const int NT = K >> 6;
    auto stage = [&](int t, int buf) {
        const h16* a = ag + (long long)t * 64;
        const h16* b = bg + (long long)t * 64;
        h16* ad = as_base + buf * (128 * 64);
        h16* bd = bs_base + buf * (128 * 64);
        #pragma unroll
        for (int i = 0; i < 4; ++i) {
            __builtin_amdgcn_global_load_lds(
                (const __attribute__((address_space(1))) void*)(a + (long long)i * 8 * ldA),
                (__attribute__((address_space(3))) void*)(ad + i * 8 * 64), 16, 0, 0);
            __builtin_amdgcn_global_load_lds(
                (const __attribute__((address_space(1))) void*)(b + (long long)i * 8 * ldbt),
                (__attribute__((address_space(3))) void*)(bd + i * 8 * 64), 16, 0, 0);
        }
    };

    stage(0, 0);
    int cur = 0;
    for (int t = 0; t < NT; ++t) {
        if (t + 1 < NT) {
            stage(t + 1, cur ^ 1);                           // next tile in flight across MFMA
            asm volatile("s_waitcnt vmcnt(8)" ::: "memory"); // wait only for buf[cur]'s 8 loads
        } else {
            asm volatile("s_waitcnt vmcnt(0)" ::: "memory");
        }
        __builtin_amdgcn_s_barrier();
        const h16* Ab = As + cur * (128 * 64);
        const h16* Bb2 = Bs + cur * (128 * 64);
        #pragma unroll
        for (int kk = 0; kk < 2; ++kk) {
            const int c = kk * 4 + g;
            const int slot = (c ^ (l15 & 7)) << 3;
            f16x8 af[4], bb[4];
            #pragma unroll
            for (int i = 0; i < 4; ++i) {
                af[i] = *(const f16x8*)(Ab + (wm + i * 16 + l15) * 64 + slot);
                bb[i] = *(const f16x8*)(Bb2 + (wn + i * 16 + l15) * 64 + slot);
            }
            #pragma unroll
            for (int i = 0; i < 4; ++i)
                #pragma unroll
                for (int j = 0; j < 4; ++j)
                    acc[i][j] = __builtin_amdgcn_mfma_f32_16x16x32_f16(af[i], bb[j], acc[i][j], 0, 0, 0);
        }
        __builtin_amdgcn_s_barrier();
        cur ^= 1;
    }

    #pragma unroll
    for (int j = 0; j < 4; ++j) {
        int col = col0 + wn + j * 16 + l15;
        int grp = col >> 8;
        long long cb = (long long)grp * ostride + (col & 255);
        float bv = bias ? bias[col] : 0.f;
        #pragma unroll
        for (int i = 0; i < 4; ++i) {
            #pragma unroll
            for (int r = 0; r < 4; ++r) {
                long long row = row0 + wm + i * 16 + g * 4 + r;
                float v = acc[i][j][r] + bv;
                if (relu) v = fmaxf(v, 0.f);
                long long addr = cb + row * ldc;
                if (Cadd) v += b2f(Cadd[addr]);
                C[addr] = f2b(v);
            }
        }
    }
}

// ---------------- MFMA GEMM (128x256, 8 waves) + residual + LayerNorm, 2-phase pipeline ----------------
__global__ __launch_bounds__(512) void k_gemm_ln(const h16* __restrict__ A, const h16* __restrict__ Bt,
                                                 const float* __restrict__ bias, const h16* __restrict__ Cadd,
                                                 const h16* __restrict__ R,
                                                 const float* __restrict__ gw, const float* __restrict__ bw,
                                                 h16* __restrict__ O16, float* __restrict__ O32,
                                                 int K, int ldA, int ldbt, int HW, int mode)
{
    __shared__ __align__(16) h16 As[2 * 128 * 64];
    __shared__ __align__(16) h16 Bs[2 * 256 * 64];
    __shared__ float red[2][128][4];
    const int tid = threadIdx.x;
    const int wave = tid >> 6, lane = tid & 63;
    const int l15 = lane & 15, g = lane >> 4;
    const int row0 = blockIdx.x * 128;
    const int wm = (wave >> 2) * 64, wn = (wave & 3) * 64;

    f32x4 acc[4][4] = {};

    const int ar = wave * 16 + (lane >> 3);
    const int br = wave * 32 + (lane >> 3);
    const int ach = ((lane & 7) ^ (ar & 7)) * 8;
    const int bch = ((lane & 7) ^ (br & 7)) * 8;
    const h16* ag = A  + (long long)(row0 + ar) * ldA + ach;
    const h16* bg = Bt + (long long)br * ldbt + bch;
    h16* as_base = As + (wave * 16) * 64;
    h16* bs_base = Bs + (wave * 32) * 64;

    const int NT = K >> 6;
    auto stage = [&](int t, int buf) {
        const h16* a = ag + (long long)t * 64;
        const h16* b = bg + (long long)t * 64;
        h16* ad = as_base + buf * (128 * 64);
        h16* bd = bs_base + buf * (256 * 64);
        #pragma unroll
        for (int i = 0; i < 2; ++i)
            __builtin_amdgcn_global_load_lds(
                (const __attribute__((address_space(1))) void*)(a + (long long)i * 8 * ldA),
                (__attribute__((address_space(3))) void*)(ad + i * 8 * 64), 16, 0, 0);
        #pragma unroll
        for (int i = 0; i < 4; ++i)
            __builtin_amdgcn_global_load_lds(
                (const __attribute__((address_space(1))) void*)(b + (long long)i * 8 * ldbt),
                (__attribute__((address_space(3))) void*)(bd + i * 8 * 64), 16, 0, 0);
    };

    stage(0, 0);
    int cur = 0;
    for (int t = 0; t < NT; ++t) {
        if (t + 1 < NT) {
            stage(t + 1, cur ^ 1);
            asm volatile("s_waitcnt vmcnt(6)" ::: "memory");
        } else {
            asm volatile("s_waitcnt vmcnt(0)" ::: "memory");
        }
        __builtin_amdgcn_s_barrier();
        const h16* Ab = As + cur * (128 * 64);
        const h16* Bb2 = Bs + cur * (256 * 64);
        #pragma unroll
        for (int kk = 0; kk < 2; ++kk) {
            const int c = kk * 4 + g;
            const int slot = (c ^ (l15 & 7)) << 3;
            f16x8 af[4], bb[4];
            #pragma unroll
            for (int i = 0; i < 4; ++i) {
                af[i] = *(const f16x8*)(Ab + (wm + i * 16 + l15) * 64 + slot);
                bb[i] = *(const f16x8*)(Bb2 + (wn + i * 16 + l15) * 64 + slot);
            }
            #pragma unroll
            for (int i = 0; i < 4; ++i)
                #pragma unroll
                for (int j = 0; j < 4; ++j)
                    acc[i][j] = __builtin_amdgcn_mfma_f32_16x16x32_f16(af[i], bb[j], acc[i][j], 0, 0, 0);
        }
        __builtin_amdgcn_s_barrier();
        cur ^= 1;
    }

    // epilogue: u = acc + bias + Cadd + R, per-token LN over 256 cols
    float sr[4][4] = {}, sr2[4][4] = {};
    #pragma unroll
    for (int j = 0; j < 4; ++j) {
        int col = wn + j * 16 + l15;
        float bv = bias ? bias[col] : 0.f;
        #pragma unroll
        for (int i = 0; i < 4; ++i) {
            #pragma unroll
            for (int r = 0; r < 4; ++r) {
                long long row = row0 + wm + i * 16 + g * 4 + r;
                float u = acc[i][j][r] + bv;
                if (Cadd) u += b2f(Cadd[row * CDIM + col]);
                u += b2f(R[row * CDIM + col]);
                acc[i][j][r] = u;
                sr[i][r] += u; sr2[i][r] += u * u;
            }
        }
    }
    #pragma unroll
    for (int i = 0; i < 4; ++i)
        #pragma unroll
        for (int r = 0; r < 4; ++r) {
            float s = sr[i][r], s2 = sr2[i][r];
            #pragma unroll
            for (int off = 1; off < 16; off <<= 1) { s += __shfl_xor(s, off); s2 += __shfl_xor(s2, off); }
            sr[i][r] = s; sr2[i][r] = s2;
        }
    if (l15 == 0) {
        #pragma unroll
        for (int i = 0; i < 4; ++i)
            #pragma unroll
            for (int r = 0; r < 4; ++r) {
                int lr = wm + i * 16 + g * 4 + r;
                red[0][lr][wave & 3] = sr[i][r];
                red[1][lr][wave & 3] = sr2[i][r];
            }
    }
    __syncthreads();
    float mu_[4][4], iv_[4][4];
    #pragma unroll
    for (int i = 0; i < 4; ++i)
        #pragma unroll
        for (int r = 0; r < 4; ++r) {
            int lr = wm + i * 16 + g * 4 + r;
            f32x4 p = *(const f32x4*)&red[0][lr][0];
            f32x4 q = *(const f32x4*)&red[1][lr][0];
            float ts  = p[0] + p[1] + p[2] + p[3];
            float ts2 = q[0] + q[1] + q[2] + q[3];
            float mu = ts * (1.f / 256.f);
            mu_[i][r] = mu;
            iv_[i][r] = rsqrtf(ts2 * (1.f / 256.f) - mu * mu + 1e-5f);
        }
    if (mode == 0) {
        #pragma unroll
        for (int j = 0; j < 4; ++j) {
            int col = wn + j * 16 + l15;
            float gc = gw[col], bc = bw[col];
            #pragma unroll
            for (int i = 0; i < 4; ++i)
                #pragma unroll
                for (int r = 0; r < 4; ++r) {
                    long long row = row0 + wm + i * 16 + g * 4 + r;
                    O16[row * CDIM + col] = f2b((acc[i][j][r] - mu_[i][r]) * iv_[i][r] * gc + bc);
                }
        }
    } else {
        #pragma unroll
        for (int j = 0; j < 4; ++j) {
            int col = wn + j * 16 + l15;
            float gc = gw[col], bc = bw[col];
            #pragma unroll
            for (int i = 0; i < 4; ++i) {
                int tok0 = row0 + wm + i * 16 + g * 4;
                int n = tok0 / HW, hw = tok0 - n * HW;
                f32x4 y;
                #pragma unroll
                for (int r = 0; r < 4; ++r)
                    y[r] = (acc[i][j][r] - mu_[i][r]) * iv_[i][r] * gc + bc;
                *(f32x4*)(O32 + (long long)(n * CDIM + col) * HW + hw) = y;
            }
        }
    }
}

// ---------------- MFMA windowed attention (self + cross) ----------------
__global__ __launch_bounds__(256) void k_attn_mfma(const h16* __restrict__ Q, const h16* __restrict__ Kp,
                                                   const h16* __restrict__ Vp, h16* __restrict__ O,
                                                   int Hh, int Ww, int cross)
{
    __shared__ __align__(16) h16 SpA[4][64 * 64];
    __shared__ __align__(16) h16 VtA[4][32 * 64];
    const int tid = threadIdx.x;
    const int wave = tid >> 6, lane = tid & 63;
    const int l15 = lane & 15, g = lane >> 4;
    h16* Sp = SpA[wave];
    h16* Vt = VtA[wave];

    const int win = blockIdx.x;
    int n, wi, wj;
    if (cross) { n = win >> 8; wi = (win >> 4) & 15; wj = win & 15; }
    else {
        int nw = Ww >> 3, nh = Hh >> 3;
        n = win / (nh * nw);
        int rem = win - n * (nh * nw);
        wi = rem / nw; wj = rem - (rem / nw) * nw;
    }
    auto qtok = [&](int t) {
        return cross ? (n * 128 + wi * 8 + (t >> 3)) * 128 + wj * 8 + (t & 7)
                     : (n * Hh + wi * 8 + (t >> 3)) * Ww + wj * 8 + (t & 7);
    };
    auto ktok = [&](int t) {
        return cross ? (n * 32 + ((wi * 2 + (t >> 3)) & 31)) * 32 + ((wj * 2 + (t & 7)) & 31)
                     : qtok(t);
    };
    const float scale = 0.17677669529663687f;

    int qt_frag[4], kt_frag[4];
    #pragma unroll
    for (int i = 0; i < 4; ++i) { qt_frag[i] = qtok(i * 16 + l15); kt_frag[i] = ktok(i * 16 + l15); }
    const int vtok = ktok(lane);
    int otok[4][4];
    #pragma unroll
    for (int qt = 0; qt < 4; ++qt)
        #pragma unroll
        for (int rr = 0; rr < 4; ++rr)
            otok[qt][rr] = qtok(qt * 16 + g * 4 + rr);

    #pragma unroll 1
    for (int hh = 0; hh < 2; ++hh) {
        const int h = wave * 2 + hh;
        const int hoff = h * 32;

        f16x8 vin[4];
        #pragma unroll
        for (int j = 0; j < 4; ++j)
            vin[j] = *(const f16x8*)(Vp + (long long)vtok * CDIM + hoff + j * 8);

        f16x8 kf[4], qf[4];
        #pragma unroll
        for (int i = 0; i < 4; ++i) {
            kf[i] = *(const f16x8*)(Kp + (long long)kt_frag[i] * CDIM + hoff + g * 8);
            qf[i] = *(const f16x8*)(Q  + (long long)qt_frag[i] * CDIM + hoff + g * 8);
        }

        #pragma unroll
        for (int j = 0; j < 4; ++j)
            #pragma unroll
            for (int e = 0; e < 8; ++e) {
                int d = j * 8 + e;
                Vt[(d * 64 + lane) ^ ((d & 7) << 3)] = vin[j][e];
            }

        f32x4 sT[4][4] = {};
        #pragma unroll
        for (int i = 0; i < 4; ++i)
            #pragma unroll
            for (int jq = 0; jq < 4; ++jq)
                sT[i][jq] = __builtin_amdgcn_mfma_f32_16x16x32_f16(kf[i], qf[jq], sT[i][jq], 0, 0, 0);

        #pragma unroll
        for (int jq = 0; jq < 4; ++jq) {
            float m = -1e30f;
            #pragma unroll
            for (int i = 0; i < 4; ++i)
                #pragma unroll
                for (int rr = 0; rr < 4; ++rr)
                    m = fmaxf(m, sT[i][jq][rr]);
            m = fmaxf(m, __shfl_xor(m, 16));
            m = fmaxf(m, __shfl_xor(m, 32));
            float p[16];
            float sum = 0.f;
            #pragma unroll
            for (int i = 0; i < 4; ++i)
                #pragma unroll
                for (int rr = 0; rr < 4; ++rr) {
                    float e = __expf((sT[i][jq][rr] - m) * scale);
                    p[i * 4 + rr] = e; sum += e;
                }
            sum += __shfl_xor(sum, 16);
            sum += __shfl_xor(sum, 32);
            float inv = 1.f / sum;
            int q = jq * 16 + l15;
            int rowbase = q * 64, swz = (q & 7) << 3;
            #pragma unroll
            for (int i = 0; i < 4; ++i) {
                f16x4 pk;
                pk[0] = (h16)(p[i * 4 + 0] * inv);
                pk[1] = (h16)(p[i * 4 + 1] * inv);
                pk[2] = (h16)(p[i * 4 + 2] * inv);
                pk[3] = (h16)(p[i * 4 + 3] * inv);
                *(f16x4*)(Sp + ((rowbase + i * 16 + g * 4) ^ swz)) = pk;
            }
        }
        asm volatile("s_waitcnt lgkmcnt(0)" ::: "memory");

        f32x4 o[4][2] = {};
        #pragma unroll
        for (int kb = 0; kb < 2; ++kb) {
            f16x8 vb[2];
            #pragma unroll
            for (int dt = 0; dt < 2; ++dt) {
                int d = dt * 16 + l15;
                vb[dt] = *(const f16x8*)(Vt + ((d * 64 + kb * 32 + g * 8) ^ ((d & 7) << 3)));
            }
            #pragma unroll
            for (int qt = 0; qt < 4; ++qt) {
                int q = qt * 16 + l15;
                f16x8 pa = *(const f16x8*)(Sp + ((q * 64 + kb * 32 + g * 8) ^ ((q & 7) << 3)));
                #pragma unroll
                for (int dt = 0; dt < 2; ++dt)
                    o[qt][dt] = __builtin_amdgcn_mfma_f32_16x16x32_f16(pa, vb[dt], o[qt][dt], 0, 0, 0);
            }
        }

        #pragma unroll
        for (int qt = 0; qt < 4; ++qt)
            #pragma unroll
            for (int rr = 0; rr < 4; ++rr) {
                long long tb = (long long)otok[qt][rr] * CDIM + hoff;
                #pragma unroll
                for (int dt = 0; dt < 2; ++dt)
                    O[tb + dt * 16 + l15] = f2b(o[qt][dt][rr]);
            }
        asm volatile("s_waitcnt lgkmcnt(0)" ::: "memory");
    }
}

// ---------------- final LayerNorm(A + B) -> fp32 NCHW (fallback path only) ----------------
__global__ __launch_bounds__(256) void k_ln_out(const h16* __restrict__ A, const h16* __restrict__ Bb,
                                                const float* __restrict__ g, const float* __restrict__ be,
                                                float* __restrict__ O, int HW)
{
    __shared__ float Y[32][257];
    int tid = threadIdx.x;
    int t = tid >> 5;
    int j = tid & 31;
    long long tok0 = (long long)blockIdx.x * 32;
    f32x4 g0 = *(const f32x4*)(g + j * 8),  g1 = *(const f32x4*)(g + j * 8 + 4);
    f32x4 e0 = *(const f32x4*)(be + j * 8), e1 = *(const f32x4*)(be + j * 8 + 4);
    #pragma unroll
    for (int pass = 0; pass < 4; ++pass) {
        int ta = pass * 8 + t;
        long long base = (tok0 + ta) * CDIM + j * 8;
        f16x8 a = *(const f16x8*)(A + base);
        f16x8 b = *(const f16x8*)(Bb + base);
        float v[8]; float s = 0.f, s2 = 0.f;
        #pragma unroll
        for (int e = 0; e < 8; ++e) { float vv = b2f(a[e]) + b2f(b[e]); v[e] = vv; s += vv; s2 += vv * vv; }
        #pragma unroll
        for (int off = 1; off < 32; off <<= 1) { s += __shfl_xor(s, off); s2 += __shfl_xor(s2, off); }
        float mu = s * (1.f / 256.f);
        float inv = rsqrtf(s2 * (1.f / 256.f) - mu * mu + 1e-5f);
        #pragma unroll
        for (int e = 0; e < 4; ++e) Y[ta][j * 8 + e]     = (v[e] - mu) * inv * g0[e] + e0[e];
        #pragma unroll
        for (int e = 0; e < 4; ++e) Y[ta][j * 8 + 4 + e] = (v[e + 4] - mu) * inv * g1[e] + e1[e];
    }
    __syncthreads();
    int n = (int)(tok0 / HW);
    int hw0 = (int)(tok0 - (long long)n * HW);
    int tt = tid & 31;
    int cw = tid >> 5;
    #pragma unroll
    for (int k = 0; k < 32; ++k) {
        int c = k * 8 + cw;
        O[((long long)(n * CDIM + c)) * HW + hw0 + tt] = Y[tt][c];
    }
}

// ---------------- 4x4 average pool ----------------
__global__ __launch_bounds__(256) void k_pool(const h16* __restrict__ A, h16* __restrict__ P,
                                              int Hin, int Win)
{
    int tok = blockIdx.x, c = threadIdx.x;
    int Wo = Win >> 2, Ho = Hin >> 2;
    int n = tok / (Ho * Wo);
    int rem = tok - n * (Ho * Wo);
    int i = rem / Wo, j = rem - (rem / Wo) * Wo;
    float s = 0.f;
    #pragma unroll
    for (int di = 0; di < 4; ++di)
        #pragma unroll
        for (int dj = 0; dj < 4; ++dj)
            s += b2f(A[(((long long)n * Hin + i * 4 + di) * Win + j * 4 + dj) * CDIM + c]);
    P[(long long)tok * CDIM + c] = f2b(s * 0.0625f);
}

extern "C" void kernel_launch(void* const* d_in, const int* in_sizes, int n_in,
                              void* d_out, int out_size, void* d_ws, size_t ws_size,
                              hipStream_t stream)
{
    const float* x     = (const float*)d_in[0];
    const float* sa_wq = (const float*)d_in[1];
    const float* sa_wk = (const float*)d_in[2];
    const float* sa_wv = (const float*)d_in[3];
    const float* sa_wf = (const float*)d_in[4];
    const float* sa_bf = (const float*)d_in[5];
    const float* ca_wq = (const float*)d_in[6];
    const float* ca_wk = (const float*)d_in[7];
    const float* ca_wv = (const float*)d_in[8];
    const float* ca_wf = (const float*)d_in[9];
    const float* ca_bf = (const float*)d_in[10];
    const float* lns_g = (const float*)d_in[11];
    const float* lns_b = (const float*)d_in[12];
    const float* lnc_g = (const float*)d_in[13];
    const float* lnc_b = (const float*)d_in[14];
    const float* w1    = (const float*)d_in[15];
    const float* b1    = (const float*)d_in[16];
    const float* w2    = (const float*)d_in[17];
    const float* b2    = (const float*)d_in[18];
    const float* lno_g = (const float*)d_in[19];
    const float* lno_b = (const float*)d_in[20];
    float* out = (float*)d_out;

    const int TOK0 = 8 * 128 * 128;   // 131072
    const int TOK1 = 8 * 32 * 32;     // 8192
    const size_t S0  = (size_t)TOK0 * CDIM * sizeof(h16); // 64 MiB
    const size_t SML = (size_t)TOK1 * CDIM * sizeof(h16); // 4 MiB
    char* ws = (char*)d_ws;
    h16* W0 = (h16*)(ws);
    h16* W1 = (h16*)(ws + S0);
    h16* W2 = (h16*)(ws + 2 * S0);
    h16* W3 = (h16*)(ws + 3 * S0);
    h16* H  = W2;                      // FFN hidden [TOK0][512], spans W2..W3
    h16* P1 = (h16*)(ws + 0 * SML);
    h16* Q1 = (h16*)(ws + 1 * SML);
    h16* K1 = (h16*)(ws + 2 * SML);
    h16* V1 = (h16*)(ws + 3 * SML);
    h16* A1 = (h16*)(ws + 5 * SML);
    h16* Kc = (h16*)(ws + 6 * SML);
    h16* Vc = (h16*)(ws + 7 * SML);

    const size_t WSC_BYTES = (8 * 65536 + 262144 + 262144) * sizeof(h16); // 2 MiB
    bool tailws = ws_size >= 4 * S0 + WSC_BYTES;
    h16* wsc = tailws ? (h16*)(ws + 4 * S0) : (h16*)d_out;
    h16* sa_wqT = wsc + 0 * 65536;   // [768][256] contiguous q,k,v
    h16* sa_wfT = wsc + 3 * 65536;
    h16* ca_wqT = wsc + 4 * 65536;
    h16* ca_wkT = wsc + 5 * 65536;   // [512][256] contiguous k,v
    h16* ca_wfT = wsc + 7 * 65536;
    h16* w1T    = wsc + 8 * 65536;            // [1024][256]
    h16* w2T    = wsc + 8 * 65536 + 262144;   // [256][1024]

    const long long OS0 = (long long)TOK0 * CDIM;
    const long long OS1 = (long long)TOK1 * CDIM;

    dim3 blk(256), blk2(512);

    // ---- weight prep ----
    k_wt_all<<<1024, blk, 0, stream>>>(sa_wq, sa_wk, sa_wv, sa_wf, ca_wq, ca_wk, ca_wv, ca_wf,
                                       w1, w2, wsc);

    // ---- level 0 self-attention ----
    k_nchw2nhwc<<<8 * 128 * 2 * 4, blk, 0, stream>>>(x, W0, 128, 128);
    k_gemm_mfma<<<dim3(6, TOK0 / 128), blk, 0, stream>>>(W0, sa_wqT, nullptr, nullptr, W1, 768, 256, 256, 256, 256, OS0, 0);
    k_attn_mfma<<<TOK0 / 64, blk, 0, stream>>>(W1, W2, W3, W1, 128, 128, 0);
    k_gemm_ln<<<TOK0 / 128, blk2, 0, stream>>>(W1, sa_wfT, sa_bf, nullptr, W0, lns_g, lns_b,
                                               W3, nullptr, 256, 256, 256, 16384, 0);      // W3 = A0

    // ---- level 1 self-attention ----
    k_pool<<<TOK1, blk, 0, stream>>>(W3, P1, 128, 128);
    k_gemm_mfma<<<dim3(6, TOK1 / 128), blk, 0, stream>>>(P1, sa_wqT, nullptr, nullptr, Q1, 768, 256, 256, 256, 256, OS1, 0);
    k_attn_mfma<<<TOK1 / 64, blk, 0, stream>>>(Q1, K1, V1, Q1, 32, 32, 0);
    k_gemm_ln<<<TOK1 / 128, blk2, 0, stream>>>(Q1, sa_wfT, sa_bf, nullptr, P1, lns_g, lns_b,
                                               A1, nullptr, 256, 256, 256, 1024, 0);       // A1

    // ---- cross-attention ----
    k_gemm_mfma<<<dim3(2, TOK0 / 128), blk, 0, stream>>>(W3, ca_wqT, nullptr, nullptr, W1, 256, 256, 256, 256, 256, 0, 0);
    k_gemm_mfma<<<dim3(4, TOK1 / 128), blk, 0, stream>>>(A1, ca_wkT, nullptr, nullptr, Kc, 512, 256, 256, 256, 256, OS1, 0);
    k_attn_mfma<<<TOK0 / 64, blk, 0, stream>>>(W1, Kc, Vc, W1, 0, 0, 1);
    k_gemm_ln<<<TOK0 / 128, blk2, 0, stream>>>(W1, ca_wfT, ca_bf, nullptr, W3, lnc_g, lnc_b,
                                               W1, nullptr, 256, 256, 256, 16384, 0);      // W1 = q

    // ---- FFN (hidden split 2x512 into H = W2..W3 span) + fused final LN -> fp32 NCHW ----
    k_gemm_mfma<<<dim3(4, TOK0 / 128), blk, 0, stream>>>(W1, w1T,             b1,       nullptr, H,  512, 256, 256, 256, 512, 256, 1);
    k_gemm_mfma<<<dim3(2, TOK0 / 128), blk, 0, stream>>>(H,  w2T,             b2,       nullptr, W0, 256, 512, 512, 1024, 256, 0, 0);
    k_gemm_mfma<<<dim3(4, TOK0 / 128), blk, 0, stream>>>(W1, w1T + 512 * 256, b1 + 512, nullptr, H,  512, 256, 256, 256, 512, 256, 1);
    if (tailws) {
        // fused: u = H@w2T(2nd half) + W0 + W1(residual); LN -> fp32 NCHW
        k_gemm_ln<<<TOK0 / 128, blk2, 0, stream>>>(H, w2T + 512, nullptr, W0, W1, lno_g, lno_b,
                                                   nullptr, out, 512, 512, 1024, 16384, 1);
    } else {
        // weights live in d_out -> cannot write out concurrently; two-step fallback
        k_gemm_mfma<<<dim3(2, TOK0 / 128), blk, 0, stream>>>(H, w2T + 512, nullptr, W0, W0, 256, 512, 512, 1024, 256, 0, 0);
        k_ln_out<<<TOK0 / 32, blk, 0, stream>>>(W1, W0, lno_g, lno_b, out, 16384);
    }
}